// Round 13
// baseline (258.331 us; speedup 1.0000x reference)
//
#include <hip/hip_runtime.h>

#define D_   256
#define HW_  1024
#define N_   32768
#define K_   1024

#define MAXREF   8192
#define QMARGIN  5.0e-5f   // flag margin, s-units (screen err ±8e-6 + noise 3.1e-5)
#define RMARGIN2 5.6e-5f   // bf16-based refine qualification (needs >= 4.7e-5)

typedef __attribute__((ext_vector_type(8))) short short8v;  // 8 bf16 (4 VGPRs)
typedef __attribute__((ext_vector_type(4))) float f32x4;    // MFMA acc

// async global->LDS, width 16. LDS dest wave-uniform base; global src per-lane.
#define GLDS(g, l) __builtin_amdgcn_global_load_lds( \
    (const __attribute__((address_space(1))) unsigned int*)(g), \
    (__attribute__((address_space(3))) unsigned int*)(l), 16, 0, 0)

// ws layout (bytes):
//   0 counter | 1024 list[8192] | 33792 B32 | 37888 A32
//   168960 cbAhi (512 KB) | 693248 cbAlo (512 KB)
//   1217536 vlist | 1250304 cell[8192] u64   end ~1.26 MB
// zq-region scratch: zBhi | zBlo (32 MB), consumed before gather overwrites.

// ---------------------------------------------------------------------------
__device__ __forceinline__ unsigned short f2bf_rne(float f) {
    unsigned u = __float_as_uint(f);
    unsigned r = u + 0x7FFFu + ((u >> 16) & 1u);
    return (unsigned short)(r >> 16);
}
__device__ __forceinline__ float bf2f(unsigned short h) {
    return __uint_as_float(((unsigned)h) << 16);
}

// numpy pairwise fp32 sum of squares over 256 elements (stride in elems).
__device__ __forceinline__ float np_sumsq_256(const float* a, int stride) {
    float blk[2];
    #pragma unroll
    for (int h = 0; h < 2; ++h) {
        const float* p = a + (size_t)h * 128 * stride;
        float r[8];
        #pragma unroll
        for (int j = 0; j < 8; ++j) {
            float v = p[(size_t)j * stride];
            r[j] = __fmul_rn(v, v);
        }
        for (int i = 1; i < 16; ++i) {
            #pragma unroll
            for (int j = 0; j < 8; ++j) {
                float v = p[(size_t)(i * 8 + j) * stride];
                r[j] = __fadd_rn(r[j], __fmul_rn(v, v));
            }
        }
        blk[h] = __fadd_rn(__fadd_rn(__fadd_rn(r[0], r[1]), __fadd_rn(r[2], r[3])),
                           __fadd_rn(__fadd_rn(r[4], r[5]), __fadd_rn(r[6], r[7])));
    }
    return __fadd_rn(blk[0], blk[1]);
}

// ---------------------------------------------------------------------------
// Fused prep (unchanged): bnorm(0-3) | anorm(4-131) | cbsplit(132-259) |
// init(260) | zfrag(261-4356)
// ---------------------------------------------------------------------------
__global__ __launch_bounds__(256) void prep_kernel(const float* __restrict__ z,
                                                   const float* __restrict__ cb,
                                                   float* __restrict__ A32,
                                                   float* __restrict__ B32,
                                                   short* __restrict__ cbAhi,
                                                   short* __restrict__ cbAlo,
                                                   short8v* __restrict__ zBhi,
                                                   short8v* __restrict__ zBlo,
                                                   int* __restrict__ counter) {
    const int blk = blockIdx.x;
    const int tid = threadIdx.x;
    if (blk < 4) {
        int k = blk * 256 + tid;
        B32[k] = np_sumsq_256(cb + (size_t)k * D_, 1);
    } else if (blk < 132) {
        int n  = (blk - 4) * 256 + tid;
        int b  = n >> 10;
        int hw = n & 1023;
        A32[n] = np_sumsq_256(z + (size_t)b * (D_ * HW_) + hw, HW_);
    } else if (blk < 260) {
        int c  = (blk - 132) * 256 + tid;   // 0..32767
        int kf = c >> 9;
        int ds = (c >> 6) & 7;
        int q  = (c >> 4) & 3;
        int r  = c & 15;
        int k  = kf * 16 + r;
        int d0 = ds * 32 + q * 8;
        const float* src = cb + (size_t)k * D_ + d0;
        short8v vh, vl;
        #pragma unroll
        for (int j = 0; j < 8; ++j) {
            float f = src[j];
            unsigned short h = f2bf_rne(f);
            float hf = bf2f(h);
            unsigned short l = f2bf_rne(f - hf);
            vh[j] = (short)h;
            vl[j] = (short)l;
        }
        *reinterpret_cast<short8v*>(cbAhi + (size_t)c * 8) = vh;
        *reinterpret_cast<short8v*>(cbAlo + (size_t)c * 8) = vl;
    } else if (blk == 260) {
        if (tid == 0) *counter = 0;
    } else {
        int c    = (blk - 261) * 256 + tid;  // 0..1048575
        int pxg  = c >> 9;
        int ds   = (c >> 6) & 7;
        int lane = c & 63;
        int q    = lane >> 4;
        int r    = lane & 15;
        int px   = pxg * 16 + r;
        int bb   = px >> 10;
        int hw   = px & 1023;
        int d0   = ds * 32 + q * 8;
        const float* src = z + (size_t)bb * (D_ * HW_) + hw;
        short8v vh, vl;
        #pragma unroll
        for (int j = 0; j < 8; ++j) {
            float f = src[(size_t)(d0 + j) * HW_];
            unsigned short h = f2bf_rne(f);
            float hf = bf2f(h);
            unsigned short l = f2bf_rne(f - hf);
            vh[j] = (short)h;
            vl[j] = (short)l;
        }
        zBhi[c] = vh;
        zBlo[c] = vl;
    }
}

// ---------------------------------------------------------------------------
// MFMA screening v6 (unchanged from R12): 4 waves x 64 px, LDS-staged a-frags.
// ---------------------------------------------------------------------------
__global__ __launch_bounds__(256, 2) void vq_screen6(
        const short8v* __restrict__ zBhi,
        const short8v* __restrict__ zBlo,
        const short8v* __restrict__ cbAhi,
        const short8v* __restrict__ cbAlo,
        const float* __restrict__ B32,
        float* __restrict__ oidx,
        int* __restrict__ counter,
        int* __restrict__ list,
        float* __restrict__ vlist,
        unsigned long long* __restrict__ cell)
{
    __shared__ short8v abuf[2][2048];   // 64KB double buffer

    const int tid  = threadIdx.x;
    const int lane = tid & 63;
    const int wave = tid >> 6;
    const int q    = lane >> 4;
    const int r    = lane & 15;

    const int pxgg = blockIdx.x * 4 + wave;

    short8v bhf[8], blf[8];
    #pragma unroll
    for (int ds = 0; ds < 8; ++ds) {
        bhf[ds] = zBhi[(size_t)(pxgg * 8 + ds) * 64 + lane];
        blf[ds] = zBlo[(size_t)(pxgg * 8 + ds) * 64 + lane];
    }

    const char* gbase = (wave < 2 ? (const char*)cbAhi : (const char*)cbAlo)
                      + (wave & 1) * 8192 + lane * 16;
    const int   ldsOff = (wave < 2 ? 0 : 1024) + (wave & 1) * 512;

    {
        char* d = (char*)&abuf[0][ldsOff];
        #pragma unroll
        for (int i = 0; i < 8; ++i) GLDS(gbase + i * 1024, d + i * 1024);
    }
    __syncthreads();

    float v1 = 3.4e38f, v2v = 3.4e38f;
    int   k1 = 0;

    for (int ch = 0; ch < 32; ++ch) {
        const int cur = ch & 1;
        if (ch < 31) {
            const char* s = gbase + (size_t)(ch + 1) * 16384;
            char* d = (char*)&abuf[cur ^ 1][ldsOff];
            #pragma unroll
            for (int i = 0; i < 8; ++i) GLDS(s + i * 1024, d + i * 1024);
        }

        f32x4 acc0 = {0.f,0.f,0.f,0.f};
        f32x4 acc1 = {0.f,0.f,0.f,0.f};
        #pragma unroll
        for (int ds = 0; ds < 8; ++ds) {
            short8v a0h = abuf[cur][(0 * 8 + ds) * 64 + lane];
            short8v a0l = abuf[cur][1024 + (0 * 8 + ds) * 64 + lane];
            short8v a1h = abuf[cur][(1 * 8 + ds) * 64 + lane];
            short8v a1l = abuf[cur][1024 + (1 * 8 + ds) * 64 + lane];

            acc0 = __builtin_amdgcn_mfma_f32_16x16x32_bf16(a0h, bhf[ds], acc0, 0,0,0);
            acc1 = __builtin_amdgcn_mfma_f32_16x16x32_bf16(a1h, bhf[ds], acc1, 0,0,0);
            acc0 = __builtin_amdgcn_mfma_f32_16x16x32_bf16(a0l, bhf[ds], acc0, 0,0,0);
            acc1 = __builtin_amdgcn_mfma_f32_16x16x32_bf16(a1l, bhf[ds], acc1, 0,0,0);
            acc0 = __builtin_amdgcn_mfma_f32_16x16x32_bf16(a0h, blf[ds], acc0, 0,0,0);
            acc1 = __builtin_amdgcn_mfma_f32_16x16x32_bf16(a1h, blf[ds], acc1, 0,0,0);
        }

        #pragma unroll
        for (int kf = 0; kf < 2; ++kf) {
            int kbase = ch * 32 + kf * 16 + q * 4;
            #pragma unroll
            for (int reg = 0; reg < 4; ++reg) {
                float s = 0.5f * B32[kbase + reg] - ((kf == 0) ? acc0[reg] : acc1[reg]);
                int  kk = kbase + reg;
                bool lt = s < v1;
                v2v = lt ? v1 : fminf(v2v, s);
                k1  = lt ? kk : k1;
                v1  = lt ? s  : v1;
            }
        }
        __syncthreads();
    }

    float a1 = v1, a2 = v2v;
    int   ak = k1;
    #pragma unroll
    for (int off = 16; off <= 32; off <<= 1) {
        float o1 = __shfl_xor(a1, off, 64);
        float o2 = __shfl_xor(a2, off, 64);
        int   ok = __shfl_xor(ak, off, 64);
        if (o1 < a1 || (o1 == a1 && ok < ak)) {
            a2 = fminf(a1, o2); a1 = o1; ak = ok;
        } else {
            a2 = fminf(a2, o1);
        }
    }
    if (q == 0) {
        int n = blockIdx.x * 64 + wave * 16 + r;
        oidx[n] = (float)ak;
        if (a2 - a1 < QMARGIN) {
            int slot = atomicAdd(counter, 1);
            if (slot < MAXREF) {
                list[slot]  = n;
                vlist[slot] = a1;
                cell[slot]  = 0xFFFFFFFFFFFFFFFFull;
            }
        }
    }
}

// ---------------------------------------------------------------------------
// Refinement v5: ONE WAVE per 16 flagged pixels. MFMA rescan (same fragments
// and math as screen) -> candidates (s - vref < RMARGIN2) appended to LDS list
// -> cooperative fp64 np-emulation per candidate (coalesced cb row, fixed-order
// shfl reduce) -> packed atomicMin. Replaces R12's scattered-load rescan
// (82us, VALUBusy 5.6%).
// ---------------------------------------------------------------------------
__global__ __launch_bounds__(64) void refine_mfma(
        const float* __restrict__ z,
        const float* __restrict__ cb,
        const float* __restrict__ A32,
        const float* __restrict__ B32,
        const short8v* __restrict__ zBhi,
        const short8v* __restrict__ zBlo,
        const short8v* __restrict__ cbAhi,
        const short8v* __restrict__ cbAlo,
        const int* __restrict__ counter,
        const int* __restrict__ list,
        const float* __restrict__ vlist,
        unsigned long long* __restrict__ cell)
{
    __shared__ float zs[16][257];    // exact fp32 z rows (16.4 KB)
    __shared__ int   cand[2048];     // (px<<10)|k
    __shared__ int   ccount;
    __shared__ float pv[16];
    __shared__ int   pn[16];
    __shared__ int   pslot[16];

    const int lane = threadIdx.x;    // 0..63
    const int q = lane >> 4, r = lane & 15;

    int cnt = *counter;
    if (cnt > MAXREF) cnt = MAXREF;
    const int i0 = blockIdx.x * 16;
    if (i0 >= cnt) return;

    if (lane < 16) {
        int idx   = i0 + lane;
        int valid = idx < cnt;
        pn[lane]    = list[valid ? idx : i0];
        pv[lane]    = valid ? vlist[idx] : -1e30f;   // invalid: never qualifies
        pslot[lane] = idx;
        if (lane == 0) ccount = 0;
    }
    __syncthreads();

    // stage exact fp32 z rows: lane covers px=r, d = q*64 .. q*64+63
    {
        int n  = pn[r];
        int bb = n >> 10, hw = n & 1023;
        const float* zb = z + (size_t)bb * (D_ * HW_) + hw;
        for (int j = 0; j < 64; ++j)
            zs[r][q * 64 + j] = zb[(size_t)(q * 64 + j) * HW_];
    }

    // gather b-frags for this wave's 16 pixels (same layout as screen)
    short8v bhf[8], blf[8];
    {
        int n   = pn[r];
        int pxg = n >> 4, rr = n & 15;
        #pragma unroll
        for (int ds = 0; ds < 8; ++ds) {
            bhf[ds] = zBhi[(size_t)(pxg * 8 + ds) * 64 + q * 16 + rr];
            blf[ds] = zBlo[(size_t)(pxg * 8 + ds) * 64 + q * 16 + rr];
        }
    }
    __syncthreads();

    const float pvr = pv[r];

    for (int ch = 0; ch < 32; ++ch) {
        f32x4 acc0 = {0.f,0.f,0.f,0.f};
        f32x4 acc1 = {0.f,0.f,0.f,0.f};
        #pragma unroll
        for (int ds = 0; ds < 8; ++ds) {
            int base0 = ((ch * 2 + 0) * 8 + ds) * 64 + lane;
            int base1 = ((ch * 2 + 1) * 8 + ds) * 64 + lane;
            short8v a0h = cbAhi[base0], a0l = cbAlo[base0];
            short8v a1h = cbAhi[base1], a1l = cbAlo[base1];

            acc0 = __builtin_amdgcn_mfma_f32_16x16x32_bf16(a0h, bhf[ds], acc0, 0,0,0);
            acc1 = __builtin_amdgcn_mfma_f32_16x16x32_bf16(a1h, bhf[ds], acc1, 0,0,0);
            acc0 = __builtin_amdgcn_mfma_f32_16x16x32_bf16(a0l, bhf[ds], acc0, 0,0,0);
            acc1 = __builtin_amdgcn_mfma_f32_16x16x32_bf16(a1l, bhf[ds], acc1, 0,0,0);
            acc0 = __builtin_amdgcn_mfma_f32_16x16x32_bf16(a0h, blf[ds], acc0, 0,0,0);
            acc1 = __builtin_amdgcn_mfma_f32_16x16x32_bf16(a1h, blf[ds], acc1, 0,0,0);
        }
        #pragma unroll
        for (int kf = 0; kf < 2; ++kf) {
            int kbase = ch * 32 + kf * 16 + q * 4;
            #pragma unroll
            for (int reg = 0; reg < 4; ++reg) {
                float s = 0.5f * B32[kbase + reg] - ((kf == 0) ? acc0[reg] : acc1[reg]);
                if (s - pvr < RMARGIN2) {
                    int c = atomicAdd(&ccount, 1);
                    if (c < 2048) cand[c] = (r << 10) | (kbase + reg);
                }
            }
        }
        // drain if the list could overflow next chunk (max +512/chunk)
        __syncthreads();
        if (ccount > 1536) {
            int m = ccount; if (m > 2048) m = 2048;
            for (int i = 0; i < m; ++i) {
                int pk = cand[i];
                int px = pk >> 10, k = pk & 1023;
                float4 c4 = *reinterpret_cast<const float4*>(cb + (size_t)k * D_ + lane * 4);
                double acc = 0.0;
                acc = fma((double)c4.x, (double)zs[px][lane * 4 + 0], acc);
                acc = fma((double)c4.y, (double)zs[px][lane * 4 + 1], acc);
                acc = fma((double)c4.z, (double)zs[px][lane * 4 + 2], acc);
                acc = fma((double)c4.w, (double)zs[px][lane * 4 + 3], acc);
                #pragma unroll
                for (int off = 32; off > 0; off >>= 1) acc += __shfl_down(acc, off);
                if (lane == 0) {
                    float C32 = (float)acc;
                    float d32 = __fsub_rn(__fadd_rn(A32[pn[px]], B32[k]),
                                          __fadd_rn(C32, C32));
                    unsigned long long key =
                        ((unsigned long long)__float_as_uint(d32) << 32) | (unsigned)k;
                    atomicMin(&cell[pslot[px]], key);
                }
            }
            __syncthreads();
            if (lane == 0) ccount = 0;
            __syncthreads();
        }
    }
    __syncthreads();

    // final drain
    int m = ccount; if (m > 2048) m = 2048;
    for (int i = 0; i < m; ++i) {
        int pk = cand[i];
        int px = pk >> 10, k = pk & 1023;
        float4 c4 = *reinterpret_cast<const float4*>(cb + (size_t)k * D_ + lane * 4);
        double acc = 0.0;
        acc = fma((double)c4.x, (double)zs[px][lane * 4 + 0], acc);
        acc = fma((double)c4.y, (double)zs[px][lane * 4 + 1], acc);
        acc = fma((double)c4.z, (double)zs[px][lane * 4 + 2], acc);
        acc = fma((double)c4.w, (double)zs[px][lane * 4 + 3], acc);
        #pragma unroll
        for (int off = 32; off > 0; off >>= 1) acc += __shfl_down(acc, off);
        if (lane == 0) {
            float C32 = (float)acc;
            float d32 = __fsub_rn(__fadd_rn(A32[pn[px]], B32[k]),
                                  __fadd_rn(C32, C32));
            unsigned long long key =
                ((unsigned long long)__float_as_uint(d32) << 32) | (unsigned)k;
            atomicMin(&cell[pslot[px]], key);
        }
    }
}

// ---------------------------------------------------------------------------
__global__ __launch_bounds__(256) void finalize_kernel(const int* __restrict__ counter,
                                                       const int* __restrict__ list,
                                                       const unsigned long long* __restrict__ cell,
                                                       float* __restrict__ oidx) {
    int cnt = *counter;
    if (cnt > MAXREF) cnt = MAXREF;
    for (int i = blockIdx.x * 256 + threadIdx.x; i < cnt; i += gridDim.x * 256) {
        oidx[list[i]] = (float)(unsigned)(cell[i] & 0xFFFFFFFFull);
    }
}

// ---------------------------------------------------------------------------
__global__ __launch_bounds__(256) void gather_kernel(const float* __restrict__ cb,
                                                     const float* __restrict__ oidx,
                                                     float* __restrict__ zq) {
    const int tid  = threadIdx.x;
    const int s_nl = tid & 63;
    const int s_dw = tid >> 6;
    const int p0   = blockIdx.x * 64;
    const int b    = p0 >> 10;
    const int hw0  = p0 & 1023;

    int idxn = (int)oidx[p0 + s_nl];
    const float4* crow = reinterpret_cast<const float4*>(cb + (size_t)idxn * D_);
    float* zqb = zq + (size_t)b * (D_ * HW_) + hw0;
    #pragma unroll
    for (int r = 0; r < 16; ++r) {
        int d4 = s_dw * 16 + r;
        float4 c4 = crow[d4];
        int d = d4 * 4;
        zqb[(size_t)(d + 0) * HW_ + s_nl] = c4.x;
        zqb[(size_t)(d + 1) * HW_ + s_nl] = c4.y;
        zqb[(size_t)(d + 2) * HW_ + s_nl] = c4.z;
        zqb[(size_t)(d + 3) * HW_ + s_nl] = c4.w;
    }
}

extern "C" void kernel_launch(void* const* d_in, const int* in_sizes, int n_in,
                              void* d_out, int out_size, void* d_ws, size_t ws_size,
                              hipStream_t stream) {
    const float* z  = (const float*)d_in[0];   // [32,256,32,32] fp32
    const float* cb = (const float*)d_in[1];   // [1024,256] fp32

    float* zq   = (float*)d_out;
    float* oidx = zq + (size_t)N_ * D_;

    char* ws = (char*)d_ws;
    int*                counter = (int*)(ws + 0);
    int*                list    = (int*)(ws + 1024);
    float*              B32     = (float*)(ws + 33792);
    float*              A32     = (float*)(ws + 37888);
    short*              cbAhi   = (short*)(ws + 168960);
    short*              cbAlo   = (short*)(ws + 693248);
    float*              vlist   = (float*)(ws + 1217536);
    unsigned long long* cell    = (unsigned long long*)(ws + 1250304);

    short8v* zBhi = (short8v*)zq;              // 16 MB
    short8v* zBlo = zBhi + 1048576;            // 16 MB

    prep_kernel<<<4357, 256, 0, stream>>>(z, cb, A32, B32, cbAhi, cbAlo,
                                          zBhi, zBlo, counter);
    vq_screen6<<<N_ / 64, 256, 0, stream>>>(
        zBhi, zBlo, (const short8v*)cbAhi, (const short8v*)cbAlo, B32,
        oidx, counter, list, vlist, cell);
    refine_mfma<<<MAXREF / 16, 64, 0, stream>>>(
        z, cb, A32, B32, zBhi, zBlo,
        (const short8v*)cbAhi, (const short8v*)cbAlo,
        counter, list, vlist, cell);
    finalize_kernel<<<32, 256, 0, stream>>>(counter, list, cell, oidx);
    gather_kernel<<<N_ / 64, 256, 0, stream>>>(cb, oidx, zq);
}

// Round 14
// 213.187 us; speedup vs baseline: 1.2118x; 1.2118x over previous
//
#include <hip/hip_runtime.h>

#define D_   256
#define HW_  1024
#define N_   32768
#define K_   1024

#define QMARGIN  5.0e-5f   // flag margin, s-units
#define RMARGIN2 5.6e-5f   // candidate margin (bf16 screen err + d32 noise, >= 4.7e-5)
#define CANDCAP  1536

typedef __attribute__((ext_vector_type(8))) short short8v;  // 8 bf16 (4 VGPRs)
typedef __attribute__((ext_vector_type(4))) float f32x4;    // MFMA acc

#define GLDS(g, l) __builtin_amdgcn_global_load_lds( \
    (const __attribute__((address_space(1))) unsigned int*)(g), \
    (__attribute__((address_space(3))) unsigned int*)(l), 16, 0, 0)

// ws layout (bytes):
//   33792 B32[1024] | 37888 A32[32768]
//   168960 cbAhi (512 KB) | 693248 cbAlo (512 KB)
// zq-region scratch: zBhi | zBlo (32 MB), consumed before gather overwrites.

// ---------------------------------------------------------------------------
__device__ __forceinline__ unsigned short f2bf_rne(float f) {
    unsigned u = __float_as_uint(f);
    unsigned r = u + 0x7FFFu + ((u >> 16) & 1u);
    return (unsigned short)(r >> 16);
}
__device__ __forceinline__ float bf2f(unsigned short h) {
    return __uint_as_float(((unsigned)h) << 16);
}

// numpy pairwise fp32 sum of squares over 256 elements (stride in elems).
__device__ __forceinline__ float np_sumsq_256(const float* a, int stride) {
    float blk[2];
    #pragma unroll
    for (int h = 0; h < 2; ++h) {
        const float* p = a + (size_t)h * 128 * stride;
        float r[8];
        #pragma unroll
        for (int j = 0; j < 8; ++j) {
            float v = p[(size_t)j * stride];
            r[j] = __fmul_rn(v, v);
        }
        for (int i = 1; i < 16; ++i) {
            #pragma unroll
            for (int j = 0; j < 8; ++j) {
                float v = p[(size_t)(i * 8 + j) * stride];
                r[j] = __fadd_rn(r[j], __fmul_rn(v, v));
            }
        }
        blk[h] = __fadd_rn(__fadd_rn(__fadd_rn(r[0], r[1]), __fadd_rn(r[2], r[3])),
                           __fadd_rn(__fadd_rn(r[4], r[5]), __fadd_rn(r[6], r[7])));
    }
    return __fadd_rn(blk[0], blk[1]);
}

// ---------------------------------------------------------------------------
// Fused prep: bnorm(0-3) | anorm(4-131) | cbsplit(132-259) | zfrag(260-4355)
// ---------------------------------------------------------------------------
__global__ __launch_bounds__(256) void prep_kernel(const float* __restrict__ z,
                                                   const float* __restrict__ cb,
                                                   float* __restrict__ A32,
                                                   float* __restrict__ B32,
                                                   short* __restrict__ cbAhi,
                                                   short* __restrict__ cbAlo,
                                                   short8v* __restrict__ zBhi,
                                                   short8v* __restrict__ zBlo) {
    const int blk = blockIdx.x;
    const int tid = threadIdx.x;
    if (blk < 4) {
        int k = blk * 256 + tid;
        B32[k] = np_sumsq_256(cb + (size_t)k * D_, 1);
    } else if (blk < 132) {
        int n  = (blk - 4) * 256 + tid;
        int b  = n >> 10;
        int hw = n & 1023;
        A32[n] = np_sumsq_256(z + (size_t)b * (D_ * HW_) + hw, HW_);
    } else if (blk < 260) {
        int c  = (blk - 132) * 256 + tid;   // 0..32767
        int kf = c >> 9;
        int ds = (c >> 6) & 7;
        int q  = (c >> 4) & 3;
        int r  = c & 15;
        int k  = kf * 16 + r;
        int d0 = ds * 32 + q * 8;
        const float* src = cb + (size_t)k * D_ + d0;
        short8v vh, vl;
        #pragma unroll
        for (int j = 0; j < 8; ++j) {
            float f = src[j];
            unsigned short h = f2bf_rne(f);
            float hf = bf2f(h);
            unsigned short l = f2bf_rne(f - hf);
            vh[j] = (short)h;
            vl[j] = (short)l;
        }
        *reinterpret_cast<short8v*>(cbAhi + (size_t)c * 8) = vh;
        *reinterpret_cast<short8v*>(cbAlo + (size_t)c * 8) = vl;
    } else {
        int c    = (blk - 260) * 256 + tid;  // 0..1048575
        int pxg  = c >> 9;
        int ds   = (c >> 6) & 7;
        int lane = c & 63;
        int q    = lane >> 4;
        int r    = lane & 15;
        int px   = pxg * 16 + r;
        int bb   = px >> 10;
        int hw   = px & 1023;
        int d0   = ds * 32 + q * 8;
        const float* src = z + (size_t)bb * (D_ * HW_) + hw;
        short8v vh, vl;
        #pragma unroll
        for (int j = 0; j < 8; ++j) {
            float f = src[(size_t)(d0 + j) * HW_];
            unsigned short h = f2bf_rne(f);
            float hf = bf2f(h);
            unsigned short l = f2bf_rne(f - hf);
            vh[j] = (short)h;
            vl[j] = (short)l;
        }
        zBhi[c] = vh;
        zBlo[c] = vl;
    }
}

// ---------------------------------------------------------------------------
// Screening v7: v6 structure (4 waves x 64 px, LDS-staged a-frags) + fused
// candidate capture (prefix-min margin appends) + in-block fp64 resolution
// of flagged pixels. No separate refine/finalize kernels.
// ---------------------------------------------------------------------------
__global__ __launch_bounds__(256, 2) void vq_screen7(
        const float* __restrict__ z,
        const short8v* __restrict__ zBhi,
        const short8v* __restrict__ zBlo,
        const short8v* __restrict__ cbAhi,
        const short8v* __restrict__ cbAlo,
        const float* __restrict__ A32,
        const float* __restrict__ B32,
        const float* __restrict__ cb,
        float* __restrict__ oidx)
{
    __shared__ short8v abuf[2][2048];   // 64 KB double buffer
    __shared__ int     cpk[CANDCAP];    // (px<<10)|k
    __shared__ float   cs[CANDCAP];     // screen s of candidate
    __shared__ float   vfin[64];
    __shared__ int     flg[64];
    __shared__ float   zrow[256];
    __shared__ int     ccount;

    const int tid  = threadIdx.x;
    const int lane = tid & 63;
    const int wave = tid >> 6;
    const int q    = lane >> 4;
    const int r    = lane & 15;
    const int pxl  = wave * 16 + r;    // this lane's pixel (same for all 4 q-lanes)

    const int pxgg = blockIdx.x * 4 + wave;

    if (tid == 0) ccount = 0;

    short8v bhf[8], blf[8];
    #pragma unroll
    for (int ds = 0; ds < 8; ++ds) {
        bhf[ds] = zBhi[(size_t)(pxgg * 8 + ds) * 64 + lane];
        blf[ds] = zBlo[(size_t)(pxgg * 8 + ds) * 64 + lane];
    }

    const char* gbase = (wave < 2 ? (const char*)cbAhi : (const char*)cbAlo)
                      + (wave & 1) * 8192 + lane * 16;
    const int   ldsOff = (wave < 2 ? 0 : 1024) + (wave & 1) * 512;

    {
        char* d = (char*)&abuf[0][ldsOff];
        #pragma unroll
        for (int i = 0; i < 8; ++i) GLDS(gbase + i * 1024, d + i * 1024);
    }
    __syncthreads();

    float v1 = 3.4e38f, v2v = 3.4e38f;
    int   k1 = 0;
    float pmin = 3.4e38f;

    for (int ch = 0; ch < 32; ++ch) {
        const int cur = ch & 1;
        if (ch < 31) {
            const char* s = gbase + (size_t)(ch + 1) * 16384;
            char* d = (char*)&abuf[cur ^ 1][ldsOff];
            #pragma unroll
            for (int i = 0; i < 8; ++i) GLDS(s + i * 1024, d + i * 1024);
        }

        f32x4 acc0 = {0.f,0.f,0.f,0.f};
        f32x4 acc1 = {0.f,0.f,0.f,0.f};
        #pragma unroll
        for (int ds = 0; ds < 8; ++ds) {
            short8v a0h = abuf[cur][(0 * 8 + ds) * 64 + lane];
            short8v a0l = abuf[cur][1024 + (0 * 8 + ds) * 64 + lane];
            short8v a1h = abuf[cur][(1 * 8 + ds) * 64 + lane];
            short8v a1l = abuf[cur][1024 + (1 * 8 + ds) * 64 + lane];

            acc0 = __builtin_amdgcn_mfma_f32_16x16x32_bf16(a0h, bhf[ds], acc0, 0,0,0);
            acc1 = __builtin_amdgcn_mfma_f32_16x16x32_bf16(a1h, bhf[ds], acc1, 0,0,0);
            acc0 = __builtin_amdgcn_mfma_f32_16x16x32_bf16(a0l, bhf[ds], acc0, 0,0,0);
            acc1 = __builtin_amdgcn_mfma_f32_16x16x32_bf16(a1l, bhf[ds], acc1, 0,0,0);
            acc0 = __builtin_amdgcn_mfma_f32_16x16x32_bf16(a0h, blf[ds], acc0, 0,0,0);
            acc1 = __builtin_amdgcn_mfma_f32_16x16x32_bf16(a1h, blf[ds], acc1, 0,0,0);
        }

        // extraction + top-2 (unchanged order) + candidate capture
        float s8[8];
        #pragma unroll
        for (int kf = 0; kf < 2; ++kf) {
            int kbase = ch * 32 + kf * 16 + q * 4;
            #pragma unroll
            for (int reg = 0; reg < 4; ++reg) {
                float s = 0.5f * B32[kbase + reg] - ((kf == 0) ? acc0[reg] : acc1[reg]);
                s8[kf * 4 + reg] = s;
                int  kk = kbase + reg;
                bool lt = s < v1;
                v2v = lt ? v1 : fminf(v2v, s);
                k1  = lt ? kk : k1;
                v1  = lt ? s  : v1;
            }
        }
        if (ch == 0) {   // two-pass chunk 0: pmin from chunk-0 merged min
            float m = fminf(fminf(fminf(s8[0], s8[1]), fminf(s8[2], s8[3])),
                            fminf(fminf(s8[4], s8[5]), fminf(s8[6], s8[7])));
            float t = fminf(m, __shfl_xor(m, 16, 64));
            pmin = fminf(t, __shfl_xor(t, 32, 64));
        }
        #pragma unroll
        for (int i = 0; i < 8; ++i) {
            if (s8[i] - pmin < RMARGIN2) {
                int c = atomicAdd(&ccount, 1);
                if (c < CANDCAP) {
                    cpk[c] = (pxl << 10) | (ch * 32 + (i >> 2) * 16 + q * 4 + (i & 3));
                    cs[c]  = s8[i];
                }
            }
        }
        {   // update pixel prefix-min for next chunk
            float t = fminf(v1, __shfl_xor(v1, 16, 64));
            pmin = fminf(t, __shfl_xor(t, 32, 64));
        }
        __syncthreads();
    }

    // final q-group top-2 merge (unchanged)
    float a1 = v1, a2 = v2v;
    int   ak = k1;
    #pragma unroll
    for (int off = 16; off <= 32; off <<= 1) {
        float o1 = __shfl_xor(a1, off, 64);
        float o2 = __shfl_xor(a2, off, 64);
        int   ok = __shfl_xor(ak, off, 64);
        if (o1 < a1 || (o1 == a1 && ok < ak)) {
            a2 = fminf(a1, o2); a1 = o1; ak = ok;
        } else {
            a2 = fminf(a2, o1);
        }
    }
    if (q == 0) {
        vfin[pxl] = a1;
        flg[pxl]  = (a2 - a1 < QMARGIN) ? 1 : 0;
        oidx[blockIdx.x * 64 + pxl] = (float)ak;
    }
    __syncthreads();

    // in-block fp64 resolution of flagged pixels
    const int ccnt = (ccount < CANDCAP) ? ccount : CANDCAP;
    for (int px = 0; px < 64; ++px) {
        if (!flg[px]) continue;
        const int n  = blockIdx.x * 64 + px;
        const int bb = n >> 10, hw = n & 1023;
        zrow[tid] = z[(size_t)bb * (D_ * HW_) + (size_t)tid * HW_ + hw];  // exact fp32
        __syncthreads();
        if (wave == 0) {
            const float vf = vfin[px];
            float bd = 3.4e38f;
            int   bk = 0x7fffffff;
            for (int i = 0; i < ccnt; ++i) {
                int pk = cpk[i];
                if ((pk >> 10) != px) continue;
                float sv = cs[i];
                if (!(sv - vf < RMARGIN2)) continue;
                int k = pk & 1023;
                float4 c4 = *reinterpret_cast<const float4*>(cb + (size_t)k * D_ + lane * 4);
                double acc = 0.0;
                acc = fma((double)c4.x, (double)zrow[lane * 4 + 0], acc);
                acc = fma((double)c4.y, (double)zrow[lane * 4 + 1], acc);
                acc = fma((double)c4.z, (double)zrow[lane * 4 + 2], acc);
                acc = fma((double)c4.w, (double)zrow[lane * 4 + 3], acc);
                #pragma unroll
                for (int off = 32; off > 0; off >>= 1) acc += __shfl_down(acc, off);
                float C32 = (float)acc;                       // valid in lane 0
                float d32 = __fsub_rn(__fadd_rn(A32[n], B32[k]), __fadd_rn(C32, C32));
                if (d32 < bd || (d32 == bd && k < bk)) { bd = d32; bk = k; }
            }
            if (lane == 0) oidx[n] = (float)bk;               // lane 0's (bd,bk) valid
        }
        __syncthreads();
    }
}

// ---------------------------------------------------------------------------
__global__ __launch_bounds__(256) void gather_kernel(const float* __restrict__ cb,
                                                     const float* __restrict__ oidx,
                                                     float* __restrict__ zq) {
    const int tid  = threadIdx.x;
    const int s_nl = tid & 63;
    const int s_dw = tid >> 6;
    const int p0   = blockIdx.x * 64;
    const int b    = p0 >> 10;
    const int hw0  = p0 & 1023;

    int idxn = (int)oidx[p0 + s_nl];
    const float4* crow = reinterpret_cast<const float4*>(cb + (size_t)idxn * D_);
    float* zqb = zq + (size_t)b * (D_ * HW_) + hw0;
    #pragma unroll
    for (int r = 0; r < 16; ++r) {
        int d4 = s_dw * 16 + r;
        float4 c4 = crow[d4];
        int d = d4 * 4;
        zqb[(size_t)(d + 0) * HW_ + s_nl] = c4.x;
        zqb[(size_t)(d + 1) * HW_ + s_nl] = c4.y;
        zqb[(size_t)(d + 2) * HW_ + s_nl] = c4.z;
        zqb[(size_t)(d + 3) * HW_ + s_nl] = c4.w;
    }
}

extern "C" void kernel_launch(void* const* d_in, const int* in_sizes, int n_in,
                              void* d_out, int out_size, void* d_ws, size_t ws_size,
                              hipStream_t stream) {
    const float* z  = (const float*)d_in[0];   // [32,256,32,32] fp32
    const float* cb = (const float*)d_in[1];   // [1024,256] fp32

    float* zq   = (float*)d_out;
    float* oidx = zq + (size_t)N_ * D_;

    char* ws = (char*)d_ws;
    float* B32   = (float*)(ws + 33792);
    float* A32   = (float*)(ws + 37888);
    short* cbAhi = (short*)(ws + 168960);
    short* cbAlo = (short*)(ws + 693248);

    short8v* zBhi = (short8v*)zq;              // 16 MB
    short8v* zBlo = zBhi + 1048576;            // 16 MB

    prep_kernel<<<4356, 256, 0, stream>>>(z, cb, A32, B32, cbAhi, cbAlo, zBhi, zBlo);
    vq_screen7<<<N_ / 64, 256, 0, stream>>>(
        z, zBhi, zBlo, (const short8v*)cbAhi, (const short8v*)cbAlo,
        A32, B32, cb, oidx);
    gather_kernel<<<N_ / 64, 256, 0, stream>>>(cb, oidx, zq);
}

// Round 15
// 130.790 us; speedup vs baseline: 1.9752x; 1.6300x over previous
//
#include <hip/hip_runtime.h>

#define D_   256
#define HW_  1024
#define N_   32768
#define K_   1024

#define MAXREF  4096
#define QMARGIN 5.0e-5f   // flag margin, s-units

typedef __attribute__((ext_vector_type(8))) short short8v;  // 8 bf16 (4 VGPRs)
typedef __attribute__((ext_vector_type(4))) float f32x4;    // MFMA acc

#define GLDS(g, l) __builtin_amdgcn_global_load_lds( \
    (const __attribute__((address_space(1))) unsigned int*)(g), \
    (__attribute__((address_space(3))) unsigned int*)(l), 16, 0, 0)

// ws layout (bytes):
//   0       counter
//   1024    list[4096] ints        (16 KB) -> 17408
//   17408   B32[1024]              (4 KB)  -> 21504
//   21504   A32[32768]             (128 KB)-> 152576
//   152576  cbAhi                  (512 KB)-> 676864
//   676864  cbAlo                  (512 KB)-> 1201152
//   1201152 ck[4096*4] ints        (64 KB) -> 1265664  (~1.21 MB total)
// zq-region scratch: zBhi | zBlo (32 MB), consumed before gather overwrites.

// ---------------------------------------------------------------------------
__device__ __forceinline__ unsigned short f2bf_rne(float f) {
    unsigned u = __float_as_uint(f);
    unsigned r = u + 0x7FFFu + ((u >> 16) & 1u);
    return (unsigned short)(r >> 16);
}
__device__ __forceinline__ float bf2f(unsigned short h) {
    return __uint_as_float(((unsigned)h) << 16);
}

// numpy pairwise fp32 sum of squares over 256 elements (stride in elems).
__device__ __forceinline__ float np_sumsq_256(const float* a, int stride) {
    float blk[2];
    #pragma unroll
    for (int h = 0; h < 2; ++h) {
        const float* p = a + (size_t)h * 128 * stride;
        float r[8];
        #pragma unroll
        for (int j = 0; j < 8; ++j) {
            float v = p[(size_t)j * stride];
            r[j] = __fmul_rn(v, v);
        }
        for (int i = 1; i < 16; ++i) {
            #pragma unroll
            for (int j = 0; j < 8; ++j) {
                float v = p[(size_t)(i * 8 + j) * stride];
                r[j] = __fadd_rn(r[j], __fmul_rn(v, v));
            }
        }
        blk[h] = __fadd_rn(__fadd_rn(__fadd_rn(r[0], r[1]), __fadd_rn(r[2], r[3])),
                           __fadd_rn(__fadd_rn(r[4], r[5]), __fadd_rn(r[6], r[7])));
    }
    return __fadd_rn(blk[0], blk[1]);
}

// ---------------------------------------------------------------------------
// Fused prep: bnorm(0-3) | anorm(4-131) | cbsplit(132-259) | init(260) |
// zfrag(261-4356)
// ---------------------------------------------------------------------------
__global__ __launch_bounds__(256) void prep_kernel(const float* __restrict__ z,
                                                   const float* __restrict__ cb,
                                                   float* __restrict__ A32,
                                                   float* __restrict__ B32,
                                                   short* __restrict__ cbAhi,
                                                   short* __restrict__ cbAlo,
                                                   short8v* __restrict__ zBhi,
                                                   short8v* __restrict__ zBlo,
                                                   int* __restrict__ counter) {
    const int blk = blockIdx.x;
    const int tid = threadIdx.x;
    if (blk < 4) {
        int k = blk * 256 + tid;
        B32[k] = np_sumsq_256(cb + (size_t)k * D_, 1);
    } else if (blk < 132) {
        int n  = (blk - 4) * 256 + tid;
        int b  = n >> 10;
        int hw = n & 1023;
        A32[n] = np_sumsq_256(z + (size_t)b * (D_ * HW_) + hw, HW_);
    } else if (blk < 260) {
        int c  = (blk - 132) * 256 + tid;   // 0..32767
        int kf = c >> 9;
        int ds = (c >> 6) & 7;
        int q  = (c >> 4) & 3;
        int r  = c & 15;
        int k  = kf * 16 + r;
        int d0 = ds * 32 + q * 8;
        const float* src = cb + (size_t)k * D_ + d0;
        short8v vh, vl;
        #pragma unroll
        for (int j = 0; j < 8; ++j) {
            float f = src[j];
            unsigned short h = f2bf_rne(f);
            float hf = bf2f(h);
            unsigned short l = f2bf_rne(f - hf);
            vh[j] = (short)h;
            vl[j] = (short)l;
        }
        *reinterpret_cast<short8v*>(cbAhi + (size_t)c * 8) = vh;
        *reinterpret_cast<short8v*>(cbAlo + (size_t)c * 8) = vl;
    } else if (blk == 260) {
        if (tid == 0) *counter = 0;
    } else {
        int c    = (blk - 261) * 256 + tid;  // 0..1048575
        int pxg  = c >> 9;
        int ds   = (c >> 6) & 7;
        int lane = c & 63;
        int q    = lane >> 4;
        int r    = lane & 15;
        int px   = pxg * 16 + r;
        int bb   = px >> 10;
        int hw   = px & 1023;
        int d0   = ds * 32 + q * 8;
        const float* src = z + (size_t)bb * (D_ * HW_) + hw;
        short8v vh, vl;
        #pragma unroll
        for (int j = 0; j < 8; ++j) {
            float f = src[(size_t)(d0 + j) * HW_];
            unsigned short h = f2bf_rne(f);
            float hf = bf2f(h);
            unsigned short l = f2bf_rne(f - hf);
            vh[j] = (short)h;
            vl[j] = (short)l;
        }
        zBhi[c] = vh;
        zBlo[c] = vl;
    }
}

// lex compare-swap: keep smaller (v,k) in (va,ka)
#define CSWAP(va, ka, vb, kb) { \
    bool sw = (vb < va) || (vb == va && kb < ka); \
    float tv = va; int tk = ka; \
    va = sw ? vb : va; ka = sw ? kb : ka; \
    vb = sw ? tv : vb; kb = sw ? tk : kb; }

// ---------------------------------------------------------------------------
// Screening v8: v6 structure + register top-4 per pixel (candidate set for
// d32 resolution). Flagged px write (n, 4 candidate k's); resolve_np finishes.
// ---------------------------------------------------------------------------
__global__ __launch_bounds__(256, 2) void vq_screen8(
        const short8v* __restrict__ zBhi,
        const short8v* __restrict__ zBlo,
        const short8v* __restrict__ cbAhi,
        const short8v* __restrict__ cbAlo,
        const float* __restrict__ B32,
        float* __restrict__ oidx,
        int* __restrict__ counter,
        int* __restrict__ list,
        int* __restrict__ ck)
{
    __shared__ short8v abuf[2][2048];   // 64 KB double buffer

    const int tid  = threadIdx.x;
    const int lane = tid & 63;
    const int wave = tid >> 6;
    const int q    = lane >> 4;
    const int r    = lane & 15;

    const int pxgg = blockIdx.x * 4 + wave;

    short8v bhf[8], blf[8];
    #pragma unroll
    for (int ds = 0; ds < 8; ++ds) {
        bhf[ds] = zBhi[(size_t)(pxgg * 8 + ds) * 64 + lane];
        blf[ds] = zBlo[(size_t)(pxgg * 8 + ds) * 64 + lane];
    }

    const char* gbase = (wave < 2 ? (const char*)cbAhi : (const char*)cbAlo)
                      + (wave & 1) * 8192 + lane * 16;
    const int   ldsOff = (wave < 2 ? 0 : 1024) + (wave & 1) * 512;

    {
        char* d = (char*)&abuf[0][ldsOff];
        #pragma unroll
        for (int i = 0; i < 8; ++i) GLDS(gbase + i * 1024, d + i * 1024);
    }
    __syncthreads();

    // register top-4 (sorted ascending, first-occurrence on ties)
    float v0 = 3.4e38f, v1 = 3.4e38f, v2 = 3.4e38f, v3 = 3.4e38f;
    int   k0 = 0x7fffffff, k1 = 0x7fffffff, k2 = 0x7fffffff, k3 = 0x7fffffff;

    for (int ch = 0; ch < 32; ++ch) {
        const int cur = ch & 1;
        if (ch < 31) {
            const char* s = gbase + (size_t)(ch + 1) * 16384;
            char* d = (char*)&abuf[cur ^ 1][ldsOff];
            #pragma unroll
            for (int i = 0; i < 8; ++i) GLDS(s + i * 1024, d + i * 1024);
        }

        f32x4 acc0 = {0.f,0.f,0.f,0.f};
        f32x4 acc1 = {0.f,0.f,0.f,0.f};
        #pragma unroll
        for (int ds = 0; ds < 8; ++ds) {
            short8v a0h = abuf[cur][(0 * 8 + ds) * 64 + lane];
            short8v a0l = abuf[cur][1024 + (0 * 8 + ds) * 64 + lane];
            short8v a1h = abuf[cur][(1 * 8 + ds) * 64 + lane];
            short8v a1l = abuf[cur][1024 + (1 * 8 + ds) * 64 + lane];

            acc0 = __builtin_amdgcn_mfma_f32_16x16x32_bf16(a0h, bhf[ds], acc0, 0,0,0);
            acc1 = __builtin_amdgcn_mfma_f32_16x16x32_bf16(a1h, bhf[ds], acc1, 0,0,0);
            acc0 = __builtin_amdgcn_mfma_f32_16x16x32_bf16(a0l, bhf[ds], acc0, 0,0,0);
            acc1 = __builtin_amdgcn_mfma_f32_16x16x32_bf16(a1l, bhf[ds], acc1, 0,0,0);
            acc0 = __builtin_amdgcn_mfma_f32_16x16x32_bf16(a0h, blf[ds], acc0, 0,0,0);
            acc1 = __builtin_amdgcn_mfma_f32_16x16x32_bf16(a1h, blf[ds], acc1, 0,0,0);
        }

        #pragma unroll
        for (int kf = 0; kf < 2; ++kf) {
            int kbase = ch * 32 + kf * 16 + q * 4;
            #pragma unroll
            for (int reg = 0; reg < 4; ++reg) {
                float s = 0.5f * B32[kbase + reg] - ((kf == 0) ? acc0[reg] : acc1[reg]);
                int  kk = kbase + reg;
                if (s < v3) {                 // rare path: sorted insert
                    if (s < v1) {
                        v3 = v2; k3 = k2;
                        v2 = v1; k2 = k1;
                        if (s < v0) { v1 = v0; k1 = k0; v0 = s; k0 = kk; }
                        else        { v1 = s;  k1 = kk; }
                    } else {
                        if (s < v2) { v3 = v2; k3 = k2; v2 = s; k2 = kk; }
                        else        { v3 = s;  k3 = kk; }
                    }
                }
            }
        }
        __syncthreads();
    }

    // merge top-4 across the 4 q-lanes (xor 16, then xor 32); bitonic merge
    #pragma unroll
    for (int off = 16; off <= 32; off <<= 1) {
        float b0 = __shfl_xor(v0, off, 64), b1 = __shfl_xor(v1, off, 64);
        float b2 = __shfl_xor(v2, off, 64), b3 = __shfl_xor(v3, off, 64);
        int   c0 = __shfl_xor(k0, off, 64), c1 = __shfl_xor(k1, off, 64);
        int   c2 = __shfl_xor(k2, off, 64), c3 = __shfl_xor(k3, off, 64);
        // stage 1: (a_i, b_{3-i}) keep min in a_i -> lower-4 bitonic
        CSWAP(v0, k0, b3, c3);
        CSWAP(v1, k1, b2, c2);
        CSWAP(v2, k2, b1, c1);
        CSWAP(v3, k3, b0, c0);
        // bitonic sort of 4: (0,2)(1,3) then (0,1)(2,3)
        CSWAP(v0, k0, v2, k2);
        CSWAP(v1, k1, v3, k3);
        CSWAP(v0, k0, v1, k1);
        CSWAP(v2, k2, v3, k3);
    }

    if (q == 0) {
        int n = blockIdx.x * 64 + wave * 16 + r;
        oidx[n] = (float)k0;
        if (v1 - v0 < QMARGIN) {
            int slot = atomicAdd(counter, 1);
            if (slot < MAXREF) {
                list[slot] = n;
                ck[slot * 4 + 0] = k0;
                ck[slot * 4 + 1] = k1;
                ck[slot * 4 + 2] = k2;
                ck[slot * 4 + 3] = k3;
            }
        }
    }
}

// ---------------------------------------------------------------------------
// Resolution: one wave per flagged pixel, 4 candidates. fp64 dot (butterfly
// reduce, deterministic) -> validated np-emulated d32 -> lex (d32,k) min.
// ---------------------------------------------------------------------------
__global__ __launch_bounds__(256) void resolve_np(const float* __restrict__ z,
                                                  const float* __restrict__ cb,
                                                  const float* __restrict__ A32,
                                                  const float* __restrict__ B32,
                                                  const int* __restrict__ counter,
                                                  const int* __restrict__ list,
                                                  const int* __restrict__ ck,
                                                  float* __restrict__ oidx) {
    int cnt = *counter;
    if (cnt > MAXREF) cnt = MAXREF;
    const int slot = blockIdx.x * 4 + (threadIdx.x >> 6);
    const int lane = threadIdx.x & 63;
    if (slot >= cnt) return;

    const int n  = list[slot];
    const int bb = n >> 10, hw = n & 1023;
    const float* zb = z + (size_t)bb * (D_ * HW_) + hw;

    float zf[4];
    #pragma unroll
    for (int j = 0; j < 4; ++j) zf[j] = zb[(size_t)(lane * 4 + j) * HW_];

    const float An = A32[n];
    float bd = 3.4e38f;
    int   bk = 0x7fffffff;
    #pragma unroll
    for (int c = 0; c < 4; ++c) {
        int k = ck[slot * 4 + c];
        float4 c4 = *reinterpret_cast<const float4*>(cb + (size_t)k * D_ + lane * 4);
        double acc = 0.0;
        acc = fma((double)c4.x, (double)zf[0], acc);
        acc = fma((double)c4.y, (double)zf[1], acc);
        acc = fma((double)c4.z, (double)zf[2], acc);
        acc = fma((double)c4.w, (double)zf[3], acc);
        #pragma unroll
        for (int off = 1; off <= 32; off <<= 1) acc += __shfl_xor(acc, off, 64);
        float C32 = (float)acc;
        float d32 = __fsub_rn(__fadd_rn(An, B32[k]), __fadd_rn(C32, C32));
        if (d32 < bd || (d32 == bd && k < bk)) { bd = d32; bk = k; }
    }
    if (lane == 0) oidx[n] = (float)bk;
}

// ---------------------------------------------------------------------------
__global__ __launch_bounds__(256) void gather_kernel(const float* __restrict__ cb,
                                                     const float* __restrict__ oidx,
                                                     float* __restrict__ zq) {
    const int tid  = threadIdx.x;
    const int s_nl = tid & 63;
    const int s_dw = tid >> 6;
    const int p0   = blockIdx.x * 64;
    const int b    = p0 >> 10;
    const int hw0  = p0 & 1023;

    int idxn = (int)oidx[p0 + s_nl];
    const float4* crow = reinterpret_cast<const float4*>(cb + (size_t)idxn * D_);
    float* zqb = zq + (size_t)b * (D_ * HW_) + hw0;
    #pragma unroll
    for (int r = 0; r < 16; ++r) {
        int d4 = s_dw * 16 + r;
        float4 c4 = crow[d4];
        int d = d4 * 4;
        zqb[(size_t)(d + 0) * HW_ + s_nl] = c4.x;
        zqb[(size_t)(d + 1) * HW_ + s_nl] = c4.y;
        zqb[(size_t)(d + 2) * HW_ + s_nl] = c4.z;
        zqb[(size_t)(d + 3) * HW_ + s_nl] = c4.w;
    }
}

extern "C" void kernel_launch(void* const* d_in, const int* in_sizes, int n_in,
                              void* d_out, int out_size, void* d_ws, size_t ws_size,
                              hipStream_t stream) {
    const float* z  = (const float*)d_in[0];   // [32,256,32,32] fp32
    const float* cb = (const float*)d_in[1];   // [1024,256] fp32

    float* zq   = (float*)d_out;
    float* oidx = zq + (size_t)N_ * D_;

    char* ws = (char*)d_ws;
    int*   counter = (int*)(ws + 0);
    int*   list    = (int*)(ws + 1024);
    float* B32     = (float*)(ws + 17408);
    float* A32     = (float*)(ws + 21504);
    short* cbAhi   = (short*)(ws + 152576);
    short* cbAlo   = (short*)(ws + 676864);
    int*   ck      = (int*)(ws + 1201152);

    short8v* zBhi = (short8v*)zq;              // 16 MB
    short8v* zBlo = zBhi + 1048576;            // 16 MB

    prep_kernel<<<4357, 256, 0, stream>>>(z, cb, A32, B32, cbAhi, cbAlo,
                                          zBhi, zBlo, counter);
    vq_screen8<<<N_ / 64, 256, 0, stream>>>(
        zBhi, zBlo, (const short8v*)cbAhi, (const short8v*)cbAlo, B32,
        oidx, counter, list, ck);
    resolve_np<<<MAXREF / 4, 256, 0, stream>>>(z, cb, A32, B32, counter, list, ck, oidx);
    gather_kernel<<<N_ / 64, 256, 0, stream>>>(cb, oidx, zq);
}

// Round 16
// 125.345 us; speedup vs baseline: 2.0610x; 1.0434x over previous
//
#include <hip/hip_runtime.h>

#define D_   256
#define HW_  1024
#define N_   32768
#define K_   1024

#define MAXREF  4096
#define QMARGIN 5.0e-5f   // flag margin, s-units

typedef __attribute__((ext_vector_type(8))) short short8v;  // 8 bf16 (4 VGPRs)
typedef __attribute__((ext_vector_type(4))) float f32x4;    // MFMA acc

#define GLDS(g, l) __builtin_amdgcn_global_load_lds( \
    (const __attribute__((address_space(1))) unsigned int*)(g), \
    (__attribute__((address_space(3))) unsigned int*)(l), 16, 0, 0)

// ws layout (bytes) — unchanged from R15:
//   0 counter | 1024 list[4096] | 17408 B32 | 21504 A32 | 152576 cbAhi |
//   676864 cbAlo | 1201152 ck[4096*4]  (~1.21 MB)
// zq-region scratch: zBhi | zBlo (32 MB), consumed before gather overwrites.

// ---------------------------------------------------------------------------
__device__ __forceinline__ unsigned short f2bf_rne(float f) {
    unsigned u = __float_as_uint(f);
    unsigned r = u + 0x7FFFu + ((u >> 16) & 1u);
    return (unsigned short)(r >> 16);
}
__device__ __forceinline__ float bf2f(unsigned short h) {
    return __uint_as_float(((unsigned)h) << 16);
}

// numpy pairwise fp32 sum of squares over 256 elements (stride in elems).
__device__ __forceinline__ float np_sumsq_256(const float* a, int stride) {
    float blk[2];
    #pragma unroll
    for (int h = 0; h < 2; ++h) {
        const float* p = a + (size_t)h * 128 * stride;
        float r[8];
        #pragma unroll
        for (int j = 0; j < 8; ++j) {
            float v = p[(size_t)j * stride];
            r[j] = __fmul_rn(v, v);
        }
        for (int i = 1; i < 16; ++i) {
            #pragma unroll
            for (int j = 0; j < 8; ++j) {
                float v = p[(size_t)(i * 8 + j) * stride];
                r[j] = __fadd_rn(r[j], __fmul_rn(v, v));
            }
        }
        blk[h] = __fadd_rn(__fadd_rn(__fadd_rn(r[0], r[1]), __fadd_rn(r[2], r[3])),
                           __fadd_rn(__fadd_rn(r[4], r[5]), __fadd_rn(r[6], r[7])));
    }
    return __fadd_rn(blk[0], blk[1]);
}

// ---------------------------------------------------------------------------
// Fused prep (unchanged): bnorm(0-3) | anorm(4-131) | cbsplit(132-259) |
// init(260) | zfrag(261-4356)
// ---------------------------------------------------------------------------
__global__ __launch_bounds__(256) void prep_kernel(const float* __restrict__ z,
                                                   const float* __restrict__ cb,
                                                   float* __restrict__ A32,
                                                   float* __restrict__ B32,
                                                   short* __restrict__ cbAhi,
                                                   short* __restrict__ cbAlo,
                                                   short8v* __restrict__ zBhi,
                                                   short8v* __restrict__ zBlo,
                                                   int* __restrict__ counter) {
    const int blk = blockIdx.x;
    const int tid = threadIdx.x;
    if (blk < 4) {
        int k = blk * 256 + tid;
        B32[k] = np_sumsq_256(cb + (size_t)k * D_, 1);
    } else if (blk < 132) {
        int n  = (blk - 4) * 256 + tid;
        int b  = n >> 10;
        int hw = n & 1023;
        A32[n] = np_sumsq_256(z + (size_t)b * (D_ * HW_) + hw, HW_);
    } else if (blk < 260) {
        int c  = (blk - 132) * 256 + tid;   // 0..32767
        int kf = c >> 9;
        int ds = (c >> 6) & 7;
        int q  = (c >> 4) & 3;
        int r  = c & 15;
        int k  = kf * 16 + r;
        int d0 = ds * 32 + q * 8;
        const float* src = cb + (size_t)k * D_ + d0;
        short8v vh, vl;
        #pragma unroll
        for (int j = 0; j < 8; ++j) {
            float f = src[j];
            unsigned short h = f2bf_rne(f);
            float hf = bf2f(h);
            unsigned short l = f2bf_rne(f - hf);
            vh[j] = (short)h;
            vl[j] = (short)l;
        }
        *reinterpret_cast<short8v*>(cbAhi + (size_t)c * 8) = vh;
        *reinterpret_cast<short8v*>(cbAlo + (size_t)c * 8) = vl;
    } else if (blk == 260) {
        if (tid == 0) *counter = 0;
    } else {
        int c    = (blk - 261) * 256 + tid;  // 0..1048575
        int pxg  = c >> 9;
        int ds   = (c >> 6) & 7;
        int lane = c & 63;
        int q    = lane >> 4;
        int r    = lane & 15;
        int px   = pxg * 16 + r;
        int bb   = px >> 10;
        int hw   = px & 1023;
        int d0   = ds * 32 + q * 8;
        const float* src = z + (size_t)bb * (D_ * HW_) + hw;
        short8v vh, vl;
        #pragma unroll
        for (int j = 0; j < 8; ++j) {
            float f = src[(size_t)(d0 + j) * HW_];
            unsigned short h = f2bf_rne(f);
            float hf = bf2f(h);
            unsigned short l = f2bf_rne(f - hf);
            vh[j] = (short)h;
            vl[j] = (short)l;
        }
        zBhi[c] = vh;
        zBlo[c] = vl;
    }
}

// lex compare-swap: keep smaller (v,k) in (va,ka)
#define CSWAP(va, ka, vb, kb) { \
    bool sw = (vb < va) || (vb == va && kb < ka); \
    float tv = va; int tk = ka; \
    va = sw ? vb : va; ka = sw ? kb : ka; \
    vb = sw ? tv : vb; kb = sw ? tk : kb; }

// sorted top-4 insert (ascending, first-occurrence ties since scan is ascending)
#define TOP4_INS(S, KK, V0,K0,V1,K1,V2,K2,V3,K3) \
    if (S < V3) { \
        if (S < V1) { \
            V3 = V2; K3 = K2; V2 = V1; K2 = K1; \
            if (S < V0) { V1 = V0; K1 = K0; V0 = S; K0 = KK; } \
            else        { V1 = S;  K1 = KK; } \
        } else { \
            if (S < V2) { V3 = V2; K3 = K2; V2 = S; K2 = KK; } \
            else        { V3 = S;  K3 = KK; } \
        } \
    }

// merge the 4 q-lanes' sorted-4 lists (xor 16 then 32): bitonic
#define QMERGE(V0,K0,V1,K1,V2,K2,V3,K3) \
    _Pragma("unroll") \
    for (int off = 16; off <= 32; off <<= 1) { \
        float b0 = __shfl_xor(V0, off, 64), b1 = __shfl_xor(V1, off, 64); \
        float b2 = __shfl_xor(V2, off, 64), b3 = __shfl_xor(V3, off, 64); \
        int   c0 = __shfl_xor(K0, off, 64), c1 = __shfl_xor(K1, off, 64); \
        int   c2 = __shfl_xor(K2, off, 64), c3 = __shfl_xor(K3, off, 64); \
        CSWAP(V0, K0, b3, c3); CSWAP(V1, K1, b2, c2); \
        CSWAP(V2, K2, b1, c1); CSWAP(V3, K3, b0, c0); \
        CSWAP(V0, K0, V2, K2); CSWAP(V1, K1, V3, K3); \
        CSWAP(V0, K0, V1, K1); CSWAP(V2, K2, V3, K3); \
    }

// ---------------------------------------------------------------------------
// Screening v9: 512 thr (8 waves) = 4 px-groups(32 px) x 2 K-halves; 128 px
// per block, grid 256 (1 block/CU, 2 waves/SIMD). Each wave: 32 px via TWO
// register b-frag sets -> same 32 ds_reads feed 2x the MFMAs (LDS-BW halved
// per pixel, R15's measured bottleneck). K-halves merged in-block via LDS.
// ---------------------------------------------------------------------------
__global__ __launch_bounds__(512) void vq_screen9(
        const short8v* __restrict__ zBhi,
        const short8v* __restrict__ zBlo,
        const short8v* __restrict__ cbAhi,
        const short8v* __restrict__ cbAlo,
        const float* __restrict__ B32,
        float* __restrict__ oidx,
        int* __restrict__ counter,
        int* __restrict__ list,
        int* __restrict__ ck)
{
    __shared__ short8v abuf[2][2][2048];   // [khalf][dbuf][hi|lo slab] = 128 KB

    const int tid  = threadIdx.x;
    const int lane = tid & 63;
    const int wave = tid >> 6;        // 0..7
    const int pxg  = wave >> 1;       // 0..3 : 32-px group
    const int kh   = wave & 1;        // K-half
    const int q    = lane >> 4;
    const int r    = lane & 15;

    // two register b-frag sets (16 px each)
    const int f0 = blockIdx.x * 8 + pxg * 2;
    short8v b0h[8], b0l[8], b1h[8], b1l[8];
    #pragma unroll
    for (int ds = 0; ds < 8; ++ds) {
        b0h[ds] = zBhi[(size_t)(f0 * 8 + ds) * 64 + lane];
        b0l[ds] = zBlo[(size_t)(f0 * 8 + ds) * 64 + lane];
        b1h[ds] = zBhi[(size_t)((f0 + 1) * 8 + ds) * 64 + lane];
        b1l[ds] = zBlo[(size_t)((f0 + 1) * 8 + ds) * 64 + lane];
    }

    // staging role: 4 waves of each khalf stage quarters of that khalf's slab
    const char* gbase = (pxg < 2 ? (const char*)cbAhi : (const char*)cbAlo)
                      + (size_t)(kh * 16) * 16384 + (pxg & 1) * 8192 + lane * 16;
    const int   ldsOff = (pxg < 2 ? 0 : 1024) + (pxg & 1) * 512;  // short8v units

    {   // prologue: stage this khalf's chunk 0 into buf 0
        char* d = (char*)&abuf[kh][0][ldsOff];
        #pragma unroll
        for (int i = 0; i < 8; ++i) GLDS(gbase + i * 1024, d + i * 1024);
    }
    __syncthreads();

    float v0a = 3.4e38f, v1a = 3.4e38f, v2a = 3.4e38f, v3a = 3.4e38f;
    int   k0a = 0x7fffffff, k1a = 0x7fffffff, k2a = 0x7fffffff, k3a = 0x7fffffff;
    float v0b = 3.4e38f, v1b = 3.4e38f, v2b = 3.4e38f, v3b = 3.4e38f;
    int   k0b = 0x7fffffff, k1b = 0x7fffffff, k2b = 0x7fffffff, k3b = 0x7fffffff;

    for (int chl = 0; chl < 16; ++chl) {
        const int cur = chl & 1;
        if (chl < 15) {
            const char* s = gbase + (size_t)(chl + 1) * 16384;
            char* d = (char*)&abuf[kh][cur ^ 1][ldsOff];
            #pragma unroll
            for (int i = 0; i < 8; ++i) GLDS(s + i * 1024, d + i * 1024);
        }

        f32x4 a00 = {0.f,0.f,0.f,0.f}, a01 = {0.f,0.f,0.f,0.f};
        f32x4 a10 = {0.f,0.f,0.f,0.f}, a11 = {0.f,0.f,0.f,0.f};
        #pragma unroll
        for (int ds = 0; ds < 8; ++ds) {
            short8v A0h = abuf[kh][cur][(0 * 8 + ds) * 64 + lane];
            short8v A0l = abuf[kh][cur][1024 + (0 * 8 + ds) * 64 + lane];
            short8v A1h = abuf[kh][cur][(1 * 8 + ds) * 64 + lane];
            short8v A1l = abuf[kh][cur][1024 + (1 * 8 + ds) * 64 + lane];

            a00 = __builtin_amdgcn_mfma_f32_16x16x32_bf16(A0h, b0h[ds], a00, 0,0,0);
            a01 = __builtin_amdgcn_mfma_f32_16x16x32_bf16(A0h, b1h[ds], a01, 0,0,0);
            a10 = __builtin_amdgcn_mfma_f32_16x16x32_bf16(A1h, b0h[ds], a10, 0,0,0);
            a11 = __builtin_amdgcn_mfma_f32_16x16x32_bf16(A1h, b1h[ds], a11, 0,0,0);
            a00 = __builtin_amdgcn_mfma_f32_16x16x32_bf16(A0l, b0h[ds], a00, 0,0,0);
            a01 = __builtin_amdgcn_mfma_f32_16x16x32_bf16(A0l, b1h[ds], a01, 0,0,0);
            a10 = __builtin_amdgcn_mfma_f32_16x16x32_bf16(A1l, b0h[ds], a10, 0,0,0);
            a11 = __builtin_amdgcn_mfma_f32_16x16x32_bf16(A1l, b1h[ds], a11, 0,0,0);
            a00 = __builtin_amdgcn_mfma_f32_16x16x32_bf16(A0h, b0l[ds], a00, 0,0,0);
            a01 = __builtin_amdgcn_mfma_f32_16x16x32_bf16(A0h, b1l[ds], a01, 0,0,0);
            a10 = __builtin_amdgcn_mfma_f32_16x16x32_bf16(A1h, b0l[ds], a10, 0,0,0);
            a11 = __builtin_amdgcn_mfma_f32_16x16x32_bf16(A1h, b1l[ds], a11, 0,0,0);
        }

        const int ch = kh * 16 + chl;
        #pragma unroll
        for (int kf = 0; kf < 2; ++kf) {
            int kbase = ch * 32 + kf * 16 + q * 4;
            #pragma unroll
            for (int reg = 0; reg < 4; ++reg) {
                float hb = 0.5f * B32[kbase + reg];
                int  kk  = kbase + reg;
                float sa = hb - ((kf == 0) ? a00[reg] : a10[reg]);
                float sb = hb - ((kf == 0) ? a01[reg] : a11[reg]);
                TOP4_INS(sa, kk, v0a,k0a, v1a,k1a, v2a,k2a, v3a,k3a);
                TOP4_INS(sb, kk, v0b,k0b, v1b,k1b, v2b,k2b, v3b,k3b);
            }
        }
        __syncthreads();
    }

    // merge the 4 q-lanes per pixel (per set)
    QMERGE(v0a,k0a, v1a,k1a, v2a,k2a, v3a,k3a);
    QMERGE(v0b,k0b, v1b,k1b, v2b,k2b, v3b,k3b);

    // ---- cross-khalf merge via LDS (reuse abuf) ----
    float* mrg = (float*)abuf;        // 128 px x 8 floats = 4 KB
    int*   mrgI = (int*)abuf;
    __syncthreads();
    if (kh == 1 && q == 0) {
        int pl0 = pxg * 32 + r;       // set a
        mrg[pl0 * 8 + 0] = v0a; mrg[pl0 * 8 + 1] = v1a;
        mrg[pl0 * 8 + 2] = v2a; mrg[pl0 * 8 + 3] = v3a;
        mrgI[pl0 * 8 + 4] = k0a; mrgI[pl0 * 8 + 5] = k1a;
        mrgI[pl0 * 8 + 6] = k2a; mrgI[pl0 * 8 + 7] = k3a;
        int pl1 = pxg * 32 + 16 + r;  // set b
        mrg[pl1 * 8 + 0] = v0b; mrg[pl1 * 8 + 1] = v1b;
        mrg[pl1 * 8 + 2] = v2b; mrg[pl1 * 8 + 3] = v3b;
        mrgI[pl1 * 8 + 4] = k0b; mrgI[pl1 * 8 + 5] = k1b;
        mrgI[pl1 * 8 + 6] = k2b; mrgI[pl1 * 8 + 7] = k3b;
    }
    __syncthreads();
    if (kh == 0 && q == 0) {
        #pragma unroll
        for (int set = 0; set < 2; ++set) {
            int pl = pxg * 32 + set * 16 + r;
            float V0 = set ? v0b : v0a, V1 = set ? v1b : v1a;
            float V2 = set ? v2b : v2a, V3 = set ? v3b : v3a;
            int   K0 = set ? k0b : k0a, K1 = set ? k1b : k1a;
            int   K2 = set ? k2b : k2a, K3 = set ? k3b : k3a;
            float o0 = mrg[pl * 8 + 0], o1 = mrg[pl * 8 + 1];
            float o2 = mrg[pl * 8 + 2], o3 = mrg[pl * 8 + 3];
            int   p0 = mrgI[pl * 8 + 4], p1 = mrgI[pl * 8 + 5];
            int   p2 = mrgI[pl * 8 + 6], p3 = mrgI[pl * 8 + 7];
            // bitonic merge of two sorted-4 lists
            CSWAP(V0, K0, o3, p3); CSWAP(V1, K1, o2, p2);
            CSWAP(V2, K2, o1, p1); CSWAP(V3, K3, o0, p0);
            CSWAP(V0, K0, V2, K2); CSWAP(V1, K1, V3, K3);
            CSWAP(V0, K0, V1, K1); CSWAP(V2, K2, V3, K3);

            int n = blockIdx.x * 128 + pl;
            oidx[n] = (float)K0;
            if (V1 - V0 < QMARGIN) {
                int slot = atomicAdd(counter, 1);
                if (slot < MAXREF) {
                    list[slot] = n;
                    ck[slot * 4 + 0] = K0;
                    ck[slot * 4 + 1] = K1;
                    ck[slot * 4 + 2] = K2;
                    ck[slot * 4 + 3] = K3;
                }
            }
        }
    }
}

// ---------------------------------------------------------------------------
// Resolution (unchanged): one wave per flagged pixel, 4 candidates.
// ---------------------------------------------------------------------------
__global__ __launch_bounds__(256) void resolve_np(const float* __restrict__ z,
                                                  const float* __restrict__ cb,
                                                  const float* __restrict__ A32,
                                                  const float* __restrict__ B32,
                                                  const int* __restrict__ counter,
                                                  const int* __restrict__ list,
                                                  const int* __restrict__ ck,
                                                  float* __restrict__ oidx) {
    int cnt = *counter;
    if (cnt > MAXREF) cnt = MAXREF;
    const int slot = blockIdx.x * 4 + (threadIdx.x >> 6);
    const int lane = threadIdx.x & 63;
    if (slot >= cnt) return;

    const int n  = list[slot];
    const int bb = n >> 10, hw = n & 1023;
    const float* zb = z + (size_t)bb * (D_ * HW_) + hw;

    float zf[4];
    #pragma unroll
    for (int j = 0; j < 4; ++j) zf[j] = zb[(size_t)(lane * 4 + j) * HW_];

    const float An = A32[n];
    float bd = 3.4e38f;
    int   bk = 0x7fffffff;
    #pragma unroll
    for (int c = 0; c < 4; ++c) {
        int k = ck[slot * 4 + c];
        float4 c4 = *reinterpret_cast<const float4*>(cb + (size_t)k * D_ + lane * 4);
        double acc = 0.0;
        acc = fma((double)c4.x, (double)zf[0], acc);
        acc = fma((double)c4.y, (double)zf[1], acc);
        acc = fma((double)c4.z, (double)zf[2], acc);
        acc = fma((double)c4.w, (double)zf[3], acc);
        #pragma unroll
        for (int off = 1; off <= 32; off <<= 1) acc += __shfl_xor(acc, off, 64);
        float C32 = (float)acc;
        float d32 = __fsub_rn(__fadd_rn(An, B32[k]), __fadd_rn(C32, C32));
        if (d32 < bd || (d32 == bd && k < bk)) { bd = d32; bk = k; }
    }
    if (lane == 0) oidx[n] = (float)bk;
}

// ---------------------------------------------------------------------------
__global__ __launch_bounds__(256) void gather_kernel(const float* __restrict__ cb,
                                                     const float* __restrict__ oidx,
                                                     float* __restrict__ zq) {
    const int tid  = threadIdx.x;
    const int s_nl = tid & 63;
    const int s_dw = tid >> 6;
    const int p0   = blockIdx.x * 64;
    const int b    = p0 >> 10;
    const int hw0  = p0 & 1023;

    int idxn = (int)oidx[p0 + s_nl];
    const float4* crow = reinterpret_cast<const float4*>(cb + (size_t)idxn * D_);
    float* zqb = zq + (size_t)b * (D_ * HW_) + hw0;
    #pragma unroll
    for (int r = 0; r < 16; ++r) {
        int d4 = s_dw * 16 + r;
        float4 c4 = crow[d4];
        int d = d4 * 4;
        zqb[(size_t)(d + 0) * HW_ + s_nl] = c4.x;
        zqb[(size_t)(d + 1) * HW_ + s_nl] = c4.y;
        zqb[(size_t)(d + 2) * HW_ + s_nl] = c4.z;
        zqb[(size_t)(d + 3) * HW_ + s_nl] = c4.w;
    }
}

extern "C" void kernel_launch(void* const* d_in, const int* in_sizes, int n_in,
                              void* d_out, int out_size, void* d_ws, size_t ws_size,
                              hipStream_t stream) {
    const float* z  = (const float*)d_in[0];   // [32,256,32,32] fp32
    const float* cb = (const float*)d_in[1];   // [1024,256] fp32

    float* zq   = (float*)d_out;
    float* oidx = zq + (size_t)N_ * D_;

    char* ws = (char*)d_ws;
    int*   counter = (int*)(ws + 0);
    int*   list    = (int*)(ws + 1024);
    float* B32     = (float*)(ws + 17408);
    float* A32     = (float*)(ws + 21504);
    short* cbAhi   = (short*)(ws + 152576);
    short* cbAlo   = (short*)(ws + 676864);
    int*   ck      = (int*)(ws + 1201152);

    short8v* zBhi = (short8v*)zq;              // 16 MB
    short8v* zBlo = zBhi + 1048576;            // 16 MB

    prep_kernel<<<4357, 256, 0, stream>>>(z, cb, A32, B32, cbAhi, cbAlo,
                                          zBhi, zBlo, counter);
    vq_screen9<<<N_ / 128, 512, 0, stream>>>(
        zBhi, zBlo, (const short8v*)cbAhi, (const short8v*)cbAlo, B32,
        oidx, counter, list, ck);
    resolve_np<<<MAXREF / 4, 256, 0, stream>>>(z, cb, A32, B32, counter, list, ck, oidx);
    gather_kernel<<<N_ / 64, 256, 0, stream>>>(cb, oidx, zq);
}

// Round 17
// 106.220 us; speedup vs baseline: 2.4320x; 1.1800x over previous
//
#include <hip/hip_runtime.h>

#define D_   256
#define HW_  1024
#define N_   32768
#define K_   1024

#define MAXREF  4096
#define QMARGIN 1.2e-4f   // fp16 screen: noise 3.1e-5 + 2*4e-5 screen err + slack

typedef __attribute__((ext_vector_type(8))) short short8v;      // (unused legacy)
typedef _Float16 half8 __attribute__((ext_vector_type(8)));     // 8 fp16 (4 VGPRs)
typedef __attribute__((ext_vector_type(4))) float f32x4;        // MFMA acc

#define GLDS(g, l) __builtin_amdgcn_global_load_lds( \
    (const __attribute__((address_space(1))) unsigned int*)(g), \
    (__attribute__((address_space(3))) unsigned int*)(l), 16, 0, 0)

// ws layout (bytes):
//   0 counter | 1024 list[4096] | 17408 B32 | 21504 A32 |
//   152576 cbAf (512 KB, fp16 codebook*1024 frags) | 1201152 ck[4096*4]
// zq-region scratch: zBf (16 MB fp16 z frags), consumed before gather.

// ---------------------------------------------------------------------------
// numpy pairwise fp32 sum of squares over 256 elements (stride in elems).
__device__ __forceinline__ float np_sumsq_256(const float* a, int stride) {
    float blk[2];
    #pragma unroll
    for (int h = 0; h < 2; ++h) {
        const float* p = a + (size_t)h * 128 * stride;
        float r[8];
        #pragma unroll
        for (int j = 0; j < 8; ++j) {
            float v = p[(size_t)j * stride];
            r[j] = __fmul_rn(v, v);
        }
        for (int i = 1; i < 16; ++i) {
            #pragma unroll
            for (int j = 0; j < 8; ++j) {
                float v = p[(size_t)(i * 8 + j) * stride];
                r[j] = __fadd_rn(r[j], __fmul_rn(v, v));
            }
        }
        blk[h] = __fadd_rn(__fadd_rn(__fadd_rn(r[0], r[1]), __fadd_rn(r[2], r[3])),
                           __fadd_rn(__fadd_rn(r[4], r[5]), __fadd_rn(r[6], r[7])));
    }
    return __fadd_rn(blk[0], blk[1]);
}

// ---------------------------------------------------------------------------
// Fused prep: bnorm(0-3) | anorm(4-131) | cbsplit(132-259) | init(260) |
// zfrag(261-4356). fp16 frags: cb scaled by 1024 (exact), z unscaled.
// ---------------------------------------------------------------------------
__global__ __launch_bounds__(256) void prep_kernel(const float* __restrict__ z,
                                                   const float* __restrict__ cb,
                                                   float* __restrict__ A32,
                                                   float* __restrict__ B32,
                                                   half8* __restrict__ cbAf,
                                                   half8* __restrict__ zBf,
                                                   int* __restrict__ counter) {
    const int blk = blockIdx.x;
    const int tid = threadIdx.x;
    if (blk < 4) {
        int k = blk * 256 + tid;
        B32[k] = np_sumsq_256(cb + (size_t)k * D_, 1);
    } else if (blk < 132) {
        int n  = (blk - 4) * 256 + tid;
        int b  = n >> 10;
        int hw = n & 1023;
        A32[n] = np_sumsq_256(z + (size_t)b * (D_ * HW_) + hw, HW_);
    } else if (blk < 260) {
        // A-fragment order: c = ((kf*8+ds)*64 + q*16 + r) holds
        // 1024*cb[k=kf*16+r][d=ds*32+q*8+j] as fp16
        int c  = (blk - 132) * 256 + tid;   // 0..32767
        int kf = c >> 9;
        int ds = (c >> 6) & 7;
        int q  = (c >> 4) & 3;
        int r  = c & 15;
        int k  = kf * 16 + r;
        int d0 = ds * 32 + q * 8;
        const float* src = cb + (size_t)k * D_ + d0;
        half8 v;
        #pragma unroll
        for (int j = 0; j < 8; ++j) v[j] = (_Float16)(src[j] * 1024.0f);
        cbAf[c] = v;
    } else if (blk == 260) {
        if (tid == 0) *counter = 0;
    } else {
        // B-fragment order: c = (pxg*8+ds)*64 + lane holds
        // z[px=pxg*16+(lane&15)][d=ds*32+(lane>>4)*8+j] as fp16
        int c    = (blk - 261) * 256 + tid;  // 0..1048575
        int pxg  = c >> 9;
        int ds   = (c >> 6) & 7;
        int lane = c & 63;
        int q    = lane >> 4;
        int r    = lane & 15;
        int px   = pxg * 16 + r;
        int bb   = px >> 10;
        int hw   = px & 1023;
        int d0   = ds * 32 + q * 8;
        const float* src = z + (size_t)bb * (D_ * HW_) + hw;
        half8 v;
        #pragma unroll
        for (int j = 0; j < 8; ++j) v[j] = (_Float16)src[(size_t)(d0 + j) * HW_];
        zBf[c] = v;
    }
}

// lex compare-swap: keep smaller (v,k) in (va,ka)
#define CSWAP(va, ka, vb, kb) { \
    bool sw = (vb < va) || (vb == va && kb < ka); \
    float tv = va; int tk = ka; \
    va = sw ? vb : va; ka = sw ? kb : ka; \
    vb = sw ? tv : vb; kb = sw ? tk : kb; }

// sorted top-4 insert (ascending, first-occurrence ties via ascending scan)
#define TOP4_INS(S, KK, V0,K0,V1,K1,V2,K2,V3,K3) \
    if (S < V3) { \
        if (S < V1) { \
            V3 = V2; K3 = K2; V2 = V1; K2 = K1; \
            if (S < V0) { V1 = V0; K1 = K0; V0 = S; K0 = KK; } \
            else        { V1 = S;  K1 = KK; } \
        } else { \
            if (S < V2) { V3 = V2; K3 = K2; V2 = S; K2 = KK; } \
            else        { V3 = S;  K3 = KK; } \
        } \
    }

// merge the 4 q-lanes' sorted-4 lists (xor 16 then 32): bitonic
#define QMERGE(V0,K0,V1,K1,V2,K2,V3,K3) \
    _Pragma("unroll") \
    for (int off = 16; off <= 32; off <<= 1) { \
        float b0 = __shfl_xor(V0, off, 64), b1 = __shfl_xor(V1, off, 64); \
        float b2 = __shfl_xor(V2, off, 64), b3 = __shfl_xor(V3, off, 64); \
        int   c0 = __shfl_xor(K0, off, 64), c1 = __shfl_xor(K1, off, 64); \
        int   c2 = __shfl_xor(K2, off, 64), c3 = __shfl_xor(K3, off, 64); \
        CSWAP(V0, K0, b3, c3); CSWAP(V1, K1, b2, c2); \
        CSWAP(V2, K2, b1, c1); CSWAP(V3, K3, b0, c0); \
        CSWAP(V0, K0, V2, K2); CSWAP(V1, K1, V3, K3); \
        CSWAP(V0, K0, V1, K1); CSWAP(V2, K2, V3, K3); \
    }

// ---------------------------------------------------------------------------
// Screening v10: single-product fp16. 512 thr = 4 px-groups(32px) x 2 K-halves,
// 128 px/block, grid 256. LDS 64 KB -> 2 blocks/CU (4 waves/SIMD). Per chunk:
// 16 ds_read_b128 + 32 MFMA (was 32+96 in bf16 3-product).
// ---------------------------------------------------------------------------
__global__ __launch_bounds__(512, 4) void vq_screen10(
        const half8* __restrict__ zBf,
        const half8* __restrict__ cbAf,
        const float* __restrict__ B32,
        float* __restrict__ oidx,
        int* __restrict__ counter,
        int* __restrict__ list,
        int* __restrict__ ck)
{
    __shared__ half8 abuf[2][2][1024];   // [khalf][dbuf][16KB slab] = 64 KB

    const int tid  = threadIdx.x;
    const int lane = tid & 63;
    const int wave = tid >> 6;        // 0..7
    const int pxg  = wave >> 1;       // 0..3 : 32-px group
    const int kh   = wave & 1;        // K-half
    const int q    = lane >> 4;
    const int r    = lane & 15;

    // two register b-frag sets (16 px each)
    const int f0 = blockIdx.x * 8 + pxg * 2;
    half8 b0[8], b1[8];
    #pragma unroll
    for (int ds = 0; ds < 8; ++ds) {
        b0[ds] = zBf[(size_t)(f0 * 8 + ds) * 64 + lane];
        b1[ds] = zBf[(size_t)((f0 + 1) * 8 + ds) * 64 + lane];
    }

    // staging: the 4 waves of each khalf stage quarters of that khalf's slab
    const char* gbase = (const char*)cbAf + (size_t)(kh * 16) * 16384
                      + pxg * 4096 + lane * 16;
    const int   ldsOff = pxg * 256;   // half8 units

    {   // prologue: stage this khalf's chunk 0 into buf 0
        char* d = (char*)&abuf[kh][0][ldsOff];
        #pragma unroll
        for (int i = 0; i < 4; ++i) GLDS(gbase + i * 1024, d + i * 1024);
    }
    __syncthreads();

    float v0a = 3.4e38f, v1a = 3.4e38f, v2a = 3.4e38f, v3a = 3.4e38f;
    int   k0a = 0x7fffffff, k1a = 0x7fffffff, k2a = 0x7fffffff, k3a = 0x7fffffff;
    float v0b = 3.4e38f, v1b = 3.4e38f, v2b = 3.4e38f, v3b = 3.4e38f;
    int   k0b = 0x7fffffff, k1b = 0x7fffffff, k2b = 0x7fffffff, k3b = 0x7fffffff;

    for (int chl = 0; chl < 16; ++chl) {
        const int cur = chl & 1;
        if (chl < 15) {
            const char* s = gbase + (size_t)(chl + 1) * 16384;
            char* d = (char*)&abuf[kh][cur ^ 1][ldsOff];
            #pragma unroll
            for (int i = 0; i < 4; ++i) GLDS(s + i * 1024, d + i * 1024);
        }

        f32x4 a00 = {0.f,0.f,0.f,0.f}, a01 = {0.f,0.f,0.f,0.f};
        f32x4 a10 = {0.f,0.f,0.f,0.f}, a11 = {0.f,0.f,0.f,0.f};
        #pragma unroll
        for (int ds = 0; ds < 8; ++ds) {
            half8 A0 = abuf[kh][cur][(0 * 8 + ds) * 64 + lane];
            half8 A1 = abuf[kh][cur][(1 * 8 + ds) * 64 + lane];
            a00 = __builtin_amdgcn_mfma_f32_16x16x32_f16(A0, b0[ds], a00, 0,0,0);
            a01 = __builtin_amdgcn_mfma_f32_16x16x32_f16(A0, b1[ds], a01, 0,0,0);
            a10 = __builtin_amdgcn_mfma_f32_16x16x32_f16(A1, b0[ds], a10, 0,0,0);
            a11 = __builtin_amdgcn_mfma_f32_16x16x32_f16(A1, b1[ds], a11, 0,0,0);
        }

        // extraction: s = hb - dot'/1024 (exact pow2 scale); min8 gate -> top4
        const int ch = kh * 16 + chl;
        float sa[8], sb[8];
        #pragma unroll
        for (int kf = 0; kf < 2; ++kf) {
            int kbase = ch * 32 + kf * 16 + q * 4;
            #pragma unroll
            for (int reg = 0; reg < 4; ++reg) {
                float hb = 0.5f * B32[kbase + reg];
                float da = (kf == 0) ? a00[reg] : a10[reg];
                float db = (kf == 0) ? a01[reg] : a11[reg];
                sa[kf * 4 + reg] = fmaf(da, -9.765625e-4f, hb);
                sb[kf * 4 + reg] = fmaf(db, -9.765625e-4f, hb);
            }
        }
        float ma = fminf(fminf(fminf(sa[0], sa[1]), fminf(sa[2], sa[3])),
                         fminf(fminf(sa[4], sa[5]), fminf(sa[6], sa[7])));
        float mb = fminf(fminf(fminf(sb[0], sb[1]), fminf(sb[2], sb[3])),
                         fminf(fminf(sb[4], sb[5]), fminf(sb[6], sb[7])));
        if (ma < v3a) {
            #pragma unroll
            for (int i = 0; i < 8; ++i) {
                int kk = ch * 32 + (i >> 2) * 16 + q * 4 + (i & 3);
                float s = sa[i];
                TOP4_INS(s, kk, v0a,k0a, v1a,k1a, v2a,k2a, v3a,k3a);
            }
        }
        if (mb < v3b) {
            #pragma unroll
            for (int i = 0; i < 8; ++i) {
                int kk = ch * 32 + (i >> 2) * 16 + q * 4 + (i & 3);
                float s = sb[i];
                TOP4_INS(s, kk, v0b,k0b, v1b,k1b, v2b,k2b, v3b,k3b);
            }
        }
        __syncthreads();
    }

    // merge the 4 q-lanes per pixel (per set)
    QMERGE(v0a,k0a, v1a,k1a, v2a,k2a, v3a,k3a);
    QMERGE(v0b,k0b, v1b,k1b, v2b,k2b, v3b,k3b);

    // ---- cross-khalf merge via LDS (reuse abuf) ----
    float* mrg = (float*)abuf;        // 128 px x 8 floats = 4 KB
    int*   mrgI = (int*)abuf;
    __syncthreads();
    if (kh == 1 && q == 0) {
        int pl0 = pxg * 32 + r;
        mrg[pl0 * 8 + 0] = v0a; mrg[pl0 * 8 + 1] = v1a;
        mrg[pl0 * 8 + 2] = v2a; mrg[pl0 * 8 + 3] = v3a;
        mrgI[pl0 * 8 + 4] = k0a; mrgI[pl0 * 8 + 5] = k1a;
        mrgI[pl0 * 8 + 6] = k2a; mrgI[pl0 * 8 + 7] = k3a;
        int pl1 = pxg * 32 + 16 + r;
        mrg[pl1 * 8 + 0] = v0b; mrg[pl1 * 8 + 1] = v1b;
        mrg[pl1 * 8 + 2] = v2b; mrg[pl1 * 8 + 3] = v3b;
        mrgI[pl1 * 8 + 4] = k0b; mrgI[pl1 * 8 + 5] = k1b;
        mrgI[pl1 * 8 + 6] = k2b; mrgI[pl1 * 8 + 7] = k3b;
    }
    __syncthreads();
    if (kh == 0 && q == 0) {
        #pragma unroll
        for (int set = 0; set < 2; ++set) {
            int pl = pxg * 32 + set * 16 + r;
            float V0 = set ? v0b : v0a, V1 = set ? v1b : v1a;
            float V2 = set ? v2b : v2a, V3 = set ? v3b : v3a;
            int   K0 = set ? k0b : k0a, K1 = set ? k1b : k1a;
            int   K2 = set ? k2b : k2a, K3 = set ? k3b : k3a;
            float o0 = mrg[pl * 8 + 0], o1 = mrg[pl * 8 + 1];
            float o2 = mrg[pl * 8 + 2], o3 = mrg[pl * 8 + 3];
            int   p0 = mrgI[pl * 8 + 4], p1 = mrgI[pl * 8 + 5];
            int   p2 = mrgI[pl * 8 + 6], p3 = mrgI[pl * 8 + 7];
            CSWAP(V0, K0, o3, p3); CSWAP(V1, K1, o2, p2);
            CSWAP(V2, K2, o1, p1); CSWAP(V3, K3, o0, p0);
            CSWAP(V0, K0, V2, K2); CSWAP(V1, K1, V3, K3);
            CSWAP(V0, K0, V1, K1); CSWAP(V2, K2, V3, K3);

            int n = blockIdx.x * 128 + pl;
            oidx[n] = (float)K0;
            if (V1 - V0 < QMARGIN) {
                int slot = atomicAdd(counter, 1);
                if (slot < MAXREF) {
                    list[slot] = n;
                    ck[slot * 4 + 0] = K0;
                    ck[slot * 4 + 1] = K1;
                    ck[slot * 4 + 2] = K2;
                    ck[slot * 4 + 3] = K3;
                }
            }
        }
    }
}

// ---------------------------------------------------------------------------
// Resolution (unchanged): one wave per flagged pixel, 4 candidates; exact
// fp64 dot -> np-emulated d32 -> lex (d32,k) min = numpy argmin semantics.
// ---------------------------------------------------------------------------
__global__ __launch_bounds__(256) void resolve_np(const float* __restrict__ z,
                                                  const float* __restrict__ cb,
                                                  const float* __restrict__ A32,
                                                  const float* __restrict__ B32,
                                                  const int* __restrict__ counter,
                                                  const int* __restrict__ list,
                                                  const int* __restrict__ ck,
                                                  float* __restrict__ oidx) {
    int cnt = *counter;
    if (cnt > MAXREF) cnt = MAXREF;
    const int slot = blockIdx.x * 4 + (threadIdx.x >> 6);
    const int lane = threadIdx.x & 63;
    if (slot >= cnt) return;

    const int n  = list[slot];
    const int bb = n >> 10, hw = n & 1023;
    const float* zb = z + (size_t)bb * (D_ * HW_) + hw;

    float zf[4];
    #pragma unroll
    for (int j = 0; j < 4; ++j) zf[j] = zb[(size_t)(lane * 4 + j) * HW_];

    const float An = A32[n];
    float bd = 3.4e38f;
    int   bk = 0x7fffffff;
    #pragma unroll
    for (int c = 0; c < 4; ++c) {
        int k = ck[slot * 4 + c];
        float4 c4 = *reinterpret_cast<const float4*>(cb + (size_t)k * D_ + lane * 4);
        double acc = 0.0;
        acc = fma((double)c4.x, (double)zf[0], acc);
        acc = fma((double)c4.y, (double)zf[1], acc);
        acc = fma((double)c4.z, (double)zf[2], acc);
        acc = fma((double)c4.w, (double)zf[3], acc);
        #pragma unroll
        for (int off = 1; off <= 32; off <<= 1) acc += __shfl_xor(acc, off, 64);
        float C32 = (float)acc;
        float d32 = __fsub_rn(__fadd_rn(An, B32[k]), __fadd_rn(C32, C32));
        if (d32 < bd || (d32 == bd && k < bk)) { bd = d32; bk = k; }
    }
    if (lane == 0) oidx[n] = (float)bk;
}

// ---------------------------------------------------------------------------
__global__ __launch_bounds__(256) void gather_kernel(const float* __restrict__ cb,
                                                     const float* __restrict__ oidx,
                                                     float* __restrict__ zq) {
    const int tid  = threadIdx.x;
    const int s_nl = tid & 63;
    const int s_dw = tid >> 6;
    const int p0   = blockIdx.x * 64;
    const int b    = p0 >> 10;
    const int hw0  = p0 & 1023;

    int idxn = (int)oidx[p0 + s_nl];
    const float4* crow = reinterpret_cast<const float4*>(cb + (size_t)idxn * D_);
    float* zqb = zq + (size_t)b * (D_ * HW_) + hw0;
    #pragma unroll
    for (int r = 0; r < 16; ++r) {
        int d4 = s_dw * 16 + r;
        float4 c4 = crow[d4];
        int d = d4 * 4;
        zqb[(size_t)(d + 0) * HW_ + s_nl] = c4.x;
        zqb[(size_t)(d + 1) * HW_ + s_nl] = c4.y;
        zqb[(size_t)(d + 2) * HW_ + s_nl] = c4.z;
        zqb[(size_t)(d + 3) * HW_ + s_nl] = c4.w;
    }
}

extern "C" void kernel_launch(void* const* d_in, const int* in_sizes, int n_in,
                              void* d_out, int out_size, void* d_ws, size_t ws_size,
                              hipStream_t stream) {
    const float* z  = (const float*)d_in[0];   // [32,256,32,32] fp32
    const float* cb = (const float*)d_in[1];   // [1024,256] fp32

    float* zq   = (float*)d_out;
    float* oidx = zq + (size_t)N_ * D_;

    char* ws = (char*)d_ws;
    int*   counter = (int*)(ws + 0);
    int*   list    = (int*)(ws + 1024);
    float* B32     = (float*)(ws + 17408);
    float* A32     = (float*)(ws + 21504);
    half8* cbAf    = (half8*)(ws + 152576);    // 512 KB
    int*   ck      = (int*)(ws + 1201152);

    half8* zBf = (half8*)zq;                   // 16 MB in zq region

    prep_kernel<<<4357, 256, 0, stream>>>(z, cb, A32, B32, cbAf, zBf, counter);
    vq_screen10<<<N_ / 128, 512, 0, stream>>>(
        zBf, cbAf, B32, oidx, counter, list, ck);
    resolve_np<<<MAXREF / 4, 256, 0, stream>>>(z, cb, A32, B32, counter, list, ck, oidx);
    gather_kernel<<<N_ / 64, 256, 0, stream>>>(cb, oidx, zq);
}

// Round 19
// 93.852 us; speedup vs baseline: 2.7525x; 1.1318x over previous
//
#include <hip/hip_runtime.h>

#define D_   256
#define HW_  1024
#define N_   32768
#define K_   1024

#define QMARGS 0.12288f   // flag margin in SCALED (1024*s) units = 1.2e-4 s-units

typedef _Float16 half8 __attribute__((ext_vector_type(8)));     // 8 fp16 (4 VGPRs)
typedef __attribute__((ext_vector_type(4))) float f32x4;        // MFMA acc

#define GLDS(g, l) __builtin_amdgcn_global_load_lds( \
    (const __attribute__((address_space(1))) unsigned int*)(g), \
    (__attribute__((address_space(3))) unsigned int*)(l), 16, 0, 0)

// ws layout (bytes)  [R18 BUG: cbAf@137216 overlapped A32 end (139264) -> fixed]:
//   0      B32[1024]   (4 KB)   -> 4096
//   4096   hbF[1024]   (4 KB)   -> 8192   = 512*B32 (scaled acc-init table)
//   8192   A32[32768]  (128 KB) -> 139264
//   139264 cbAf        (512 KB) -> 663552  (fp16 of -1024*cb in A-frag order)
// zq-region scratch: zBf (16 MB fp16 z frags), consumed before gather.

// ---------------------------------------------------------------------------
// numpy pairwise fp32 sum of squares over 256 elements (stride in elems).
__device__ __forceinline__ float np_sumsq_256(const float* a, int stride) {
    float blk[2];
    #pragma unroll
    for (int h = 0; h < 2; ++h) {
        const float* p = a + (size_t)h * 128 * stride;
        float r[8];
        #pragma unroll
        for (int j = 0; j < 8; ++j) {
            float v = p[(size_t)j * stride];
            r[j] = __fmul_rn(v, v);
        }
        for (int i = 1; i < 16; ++i) {
            #pragma unroll
            for (int j = 0; j < 8; ++j) {
                float v = p[(size_t)(i * 8 + j) * stride];
                r[j] = __fadd_rn(r[j], __fmul_rn(v, v));
            }
        }
        blk[h] = __fadd_rn(__fadd_rn(__fadd_rn(r[0], r[1]), __fadd_rn(r[2], r[3])),
                           __fadd_rn(__fadd_rn(r[4], r[5]), __fadd_rn(r[6], r[7])));
    }
    return __fadd_rn(blk[0], blk[1]);
}

// ---------------------------------------------------------------------------
// Fused prep: bnorm+hbF(0-3) | anorm(4-131) | cbsplit(132-259) | zfrag(260-4355)
// ---------------------------------------------------------------------------
__global__ __launch_bounds__(256) void prep_kernel(const float* __restrict__ z,
                                                   const float* __restrict__ cb,
                                                   float* __restrict__ A32,
                                                   float* __restrict__ B32,
                                                   float* __restrict__ hbF,
                                                   half8* __restrict__ cbAf,
                                                   half8* __restrict__ zBf) {
    const int blk = blockIdx.x;
    const int tid = threadIdx.x;
    if (blk < 4) {
        int k = blk * 256 + tid;
        float v = np_sumsq_256(cb + (size_t)k * D_, 1);
        B32[k] = v;
        hbF[k] = 512.0f * v;
    } else if (blk < 132) {
        int n  = (blk - 4) * 256 + tid;
        int b  = n >> 10;
        int hw = n & 1023;
        A32[n] = np_sumsq_256(z + (size_t)b * (D_ * HW_) + hw, HW_);
    } else if (blk < 260) {
        // A-frag order: c = ((kf*8+ds)*64 + q*16 + r) holds -1024*cb[k][d0+j]
        int c  = (blk - 132) * 256 + tid;   // 0..32767
        int kf = c >> 9;
        int ds = (c >> 6) & 7;
        int q  = (c >> 4) & 3;
        int r  = c & 15;
        int k  = kf * 16 + r;
        int d0 = ds * 32 + q * 8;
        const float* src = cb + (size_t)k * D_ + d0;
        half8 v;
        #pragma unroll
        for (int j = 0; j < 8; ++j) v[j] = (_Float16)(src[j] * -1024.0f);
        cbAf[c] = v;
    } else {
        // B-frag order: c = (pxg*8+ds)*64 + lane holds z[px][d0+j] as fp16
        int c    = (blk - 260) * 256 + tid;  // 0..1048575
        int pxg  = c >> 9;
        int ds   = (c >> 6) & 7;
        int lane = c & 63;
        int q    = lane >> 4;
        int r    = lane & 15;
        int px   = pxg * 16 + r;
        int bb   = px >> 10;
        int hw   = px & 1023;
        int d0   = ds * 32 + q * 8;
        const float* src = z + (size_t)bb * (D_ * HW_) + hw;
        half8 v;
        #pragma unroll
        for (int j = 0; j < 8; ++j) v[j] = (_Float16)src[(size_t)(d0 + j) * HW_];
        zBf[c] = v;
    }
}

// lex compare-swap: keep smaller (v,k) in (va,ka)
#define CSWAP(va, ka, vb, kb) { \
    bool sw = (vb < va) || (vb == va && kb < ka); \
    float tv = va; int tk = ka; \
    va = sw ? vb : va; ka = sw ? kb : ka; \
    vb = sw ? tv : vb; kb = sw ? tk : kb; }

// sorted top-4 insert (ascending; ascending-k scan => first-occurrence ties)
#define TOP4_INS(S, KK, V0,K0,V1,K1,V2,K2,V3,K3) \
    if (S < V3) { \
        if (S < V1) { \
            V3 = V2; K3 = K2; V2 = V1; K2 = K1; \
            if (S < V0) { V1 = V0; K1 = K0; V0 = S; K0 = KK; } \
            else        { V1 = S;  K1 = KK; } \
        } else { \
            if (S < V2) { V3 = V2; K3 = K2; V2 = S; K2 = KK; } \
            else        { V3 = S;  K3 = KK; } \
        } \
    }

// merge the 4 q-lanes' sorted-4 lists (xor 16 then 32): bitonic
#define QMERGE(V0,K0,V1,K1,V2,K2,V3,K3) \
    _Pragma("unroll") \
    for (int off = 16; off <= 32; off <<= 1) { \
        float b0 = __shfl_xor(V0, off, 64), b1 = __shfl_xor(V1, off, 64); \
        float b2 = __shfl_xor(V2, off, 64), b3 = __shfl_xor(V3, off, 64); \
        int   c0 = __shfl_xor(K0, off, 64), c1 = __shfl_xor(K1, off, 64); \
        int   c2 = __shfl_xor(K2, off, 64), c3 = __shfl_xor(K3, off, 64); \
        CSWAP(V0, K0, b3, c3); CSWAP(V1, K1, b2, c2); \
        CSWAP(V2, K2, b1, c1); CSWAP(V3, K3, b0, c0); \
        CSWAP(V0, K0, V2, K2); CSWAP(V1, K1, V3, K3); \
        CSWAP(V0, K0, V1, K1); CSWAP(V2, K2, V3, K3); \
    }

// ---------------------------------------------------------------------------
// Screening v11: 64 px/block, grid 512 (2 independent blocks/CU). 4 waves =
// 2 px-groups(32px) x 2 K-halves. acc initialized with hbF (512*B32) and
// cbAf = -1024*c  =>  acc_final = 1024*s directly (no extraction fma).
// Flagged px resolved IN-BLOCK (exact fp64 -> np-emulated d32 on top-4).
// ---------------------------------------------------------------------------
__global__ __launch_bounds__(256, 2) void vq_screen11(
        const half8* __restrict__ zBf,
        const half8* __restrict__ cbAf,
        const float* __restrict__ hbF,
        const float* __restrict__ A32,
        const float* __restrict__ B32,
        const float* __restrict__ cb,
        const float* __restrict__ z,
        float* __restrict__ oidx)
{
    __shared__ half8 abuf[2][2][1024];   // [khalf][dbuf][16KB slab] = 64 KB
    __shared__ float mrg[64 * 8];        // 2 KB cross-khalf merge
    __shared__ int   fcount;
    __shared__ int   fn[64];
    __shared__ int   fck[64][4];

    const int tid  = threadIdx.x;
    const int lane = tid & 63;
    const int wave = tid >> 6;        // 0..3
    const int pxg  = wave >> 1;       // 0..1 : 32-px group
    const int kh   = wave & 1;        // K-half
    const int q    = lane >> 4;
    const int r    = lane & 15;

    if (tid == 0) fcount = 0;

    // two register b-frag sets (16 px each) -> 32 px per wave
    const int f0 = blockIdx.x * 4 + pxg * 2;
    half8 b0[8], b1[8];
    #pragma unroll
    for (int ds = 0; ds < 8; ++ds) {
        b0[ds] = zBf[(size_t)(f0 * 8 + ds) * 64 + lane];
        b1[ds] = zBf[(size_t)((f0 + 1) * 8 + ds) * 64 + lane];
    }

    // staging: 2 waves of each khalf stage halves of that khalf's 16KB slab
    const char* gbase = (const char*)cbAf + (size_t)(kh * 16) * 16384
                      + pxg * 8192 + lane * 16;
    const int   ldsOff = pxg * 512;   // half8 units (8KB)

    {   // prologue: stage this khalf's chunk 0 into buf 0
        char* d = (char*)&abuf[kh][0][ldsOff];
        #pragma unroll
        for (int i = 0; i < 8; ++i) GLDS(gbase + i * 1024, d + i * 1024);
    }
    __syncthreads();

    float v0a = 3.4e38f, v1a = 3.4e38f, v2a = 3.4e38f, v3a = 3.4e38f;
    int   k0a = 0x7fffffff, k1a = 0x7fffffff, k2a = 0x7fffffff, k3a = 0x7fffffff;
    float v0b = 3.4e38f, v1b = 3.4e38f, v2b = 3.4e38f, v3b = 3.4e38f;
    int   k0b = 0x7fffffff, k1b = 0x7fffffff, k2b = 0x7fffffff, k3b = 0x7fffffff;

    for (int chl = 0; chl < 16; ++chl) {
        const int cur = chl & 1;
        if (chl < 15) {
            const char* s = gbase + (size_t)(chl + 1) * 16384;
            char* d = (char*)&abuf[kh][cur ^ 1][ldsOff];
            #pragma unroll
            for (int i = 0; i < 8; ++i) GLDS(s + i * 1024, d + i * 1024);
        }

        const int ch = kh * 16 + chl;
        const float4 h0 = *reinterpret_cast<const float4*>(&hbF[ch * 32 + q * 4]);
        const float4 h1 = *reinterpret_cast<const float4*>(&hbF[ch * 32 + 16 + q * 4]);
        f32x4 a00 = {h0.x, h0.y, h0.z, h0.w};
        f32x4 a01 = a00;
        f32x4 a10 = {h1.x, h1.y, h1.z, h1.w};
        f32x4 a11 = a10;

        #pragma unroll
        for (int ds = 0; ds < 8; ++ds) {
            half8 A0 = abuf[kh][cur][(0 * 8 + ds) * 64 + lane];
            half8 A1 = abuf[kh][cur][(8 + ds) * 64 + lane];
            a00 = __builtin_amdgcn_mfma_f32_16x16x32_f16(A0, b0[ds], a00, 0,0,0);
            a01 = __builtin_amdgcn_mfma_f32_16x16x32_f16(A0, b1[ds], a01, 0,0,0);
            a10 = __builtin_amdgcn_mfma_f32_16x16x32_f16(A1, b0[ds], a10, 0,0,0);
            a11 = __builtin_amdgcn_mfma_f32_16x16x32_f16(A1, b1[ds], a11, 0,0,0);
        }

        // acc IS 1024*s. min8 gate -> sorted top-4 (ascending k order kept)
        float ma = fminf(fminf(fminf(a00[0], a00[1]), fminf(a00[2], a00[3])),
                         fminf(fminf(a10[0], a10[1]), fminf(a10[2], a10[3])));
        float mb = fminf(fminf(fminf(a01[0], a01[1]), fminf(a01[2], a01[3])),
                         fminf(fminf(a11[0], a11[1]), fminf(a11[2], a11[3])));
        if (ma < v3a) {
            #pragma unroll
            for (int i = 0; i < 8; ++i) {
                int kk  = ch * 32 + (i >> 2) * 16 + q * 4 + (i & 3);
                float s = (i < 4) ? a00[i & 3] : a10[i & 3];
                TOP4_INS(s, kk, v0a,k0a, v1a,k1a, v2a,k2a, v3a,k3a);
            }
        }
        if (mb < v3b) {
            #pragma unroll
            for (int i = 0; i < 8; ++i) {
                int kk  = ch * 32 + (i >> 2) * 16 + q * 4 + (i & 3);
                float s = (i < 4) ? a01[i & 3] : a11[i & 3];
                TOP4_INS(s, kk, v0b,k0b, v1b,k1b, v2b,k2b, v3b,k3b);
            }
        }
        __syncthreads();
    }

    // merge the 4 q-lanes per pixel (per set)
    QMERGE(v0a,k0a, v1a,k1a, v2a,k2a, v3a,k3a);
    QMERGE(v0b,k0b, v1b,k1b, v2b,k2b, v3b,k3b);

    // ---- cross-khalf merge ----
    int* mrgI = (int*)mrg;
    if (kh == 1 && q == 0) {
        int pl0 = pxg * 32 + r;
        mrg[pl0 * 8 + 0] = v0a; mrg[pl0 * 8 + 1] = v1a;
        mrg[pl0 * 8 + 2] = v2a; mrg[pl0 * 8 + 3] = v3a;
        mrgI[pl0 * 8 + 4] = k0a; mrgI[pl0 * 8 + 5] = k1a;
        mrgI[pl0 * 8 + 6] = k2a; mrgI[pl0 * 8 + 7] = k3a;
        int pl1 = pxg * 32 + 16 + r;
        mrg[pl1 * 8 + 0] = v0b; mrg[pl1 * 8 + 1] = v1b;
        mrg[pl1 * 8 + 2] = v2b; mrg[pl1 * 8 + 3] = v3b;
        mrgI[pl1 * 8 + 4] = k0b; mrgI[pl1 * 8 + 5] = k1b;
        mrgI[pl1 * 8 + 6] = k2b; mrgI[pl1 * 8 + 7] = k3b;
    }
    __syncthreads();
    if (kh == 0 && q == 0) {
        #pragma unroll
        for (int set = 0; set < 2; ++set) {
            int pl = pxg * 32 + set * 16 + r;
            float V0 = set ? v0b : v0a, V1 = set ? v1b : v1a;
            float V2 = set ? v2b : v2a, V3 = set ? v3b : v3a;
            int   K0 = set ? k0b : k0a, K1 = set ? k1b : k1a;
            int   K2 = set ? k2b : k2a, K3 = set ? k3b : k3a;
            float o0 = mrg[pl * 8 + 0], o1 = mrg[pl * 8 + 1];
            float o2 = mrg[pl * 8 + 2], o3 = mrg[pl * 8 + 3];
            int   p0 = mrgI[pl * 8 + 4], p1 = mrgI[pl * 8 + 5];
            int   p2 = mrgI[pl * 8 + 6], p3 = mrgI[pl * 8 + 7];
            CSWAP(V0, K0, o3, p3); CSWAP(V1, K1, o2, p2);
            CSWAP(V2, K2, o1, p1); CSWAP(V3, K3, o0, p0);
            CSWAP(V0, K0, V2, K2); CSWAP(V1, K1, V3, K3);
            CSWAP(V0, K0, V1, K1); CSWAP(V2, K2, V3, K3);

            int n = blockIdx.x * 64 + pl;
            oidx[n] = (float)K0;
            if (V1 - V0 < QMARGS) {
                int slot = atomicAdd(&fcount, 1);
                fn[slot] = n;
                fck[slot][0] = K0; fck[slot][1] = K1;
                fck[slot][2] = K2; fck[slot][3] = K3;
            }
        }
    }
    __syncthreads();

    // ---- in-block exact resolution of flagged pixels (one wave each) ----
    const int fc = fcount;
    for (int i = wave; i < fc; i += 4) {
        const int n  = fn[i];
        const int bb = n >> 10, hw = n & 1023;
        const float* zb = z + (size_t)bb * (D_ * HW_) + hw;
        float zf[4];
        #pragma unroll
        for (int j = 0; j < 4; ++j) zf[j] = zb[(size_t)(lane * 4 + j) * HW_];

        const float An = A32[n];
        float bd = 3.4e38f;
        int   bk = 0x7fffffff;
        #pragma unroll
        for (int c = 0; c < 4; ++c) {
            int k = fck[i][c];
            float4 c4 = *reinterpret_cast<const float4*>(cb + (size_t)k * D_ + lane * 4);
            double acc = 0.0;
            acc = fma((double)c4.x, (double)zf[0], acc);
            acc = fma((double)c4.y, (double)zf[1], acc);
            acc = fma((double)c4.z, (double)zf[2], acc);
            acc = fma((double)c4.w, (double)zf[3], acc);
            #pragma unroll
            for (int off = 1; off <= 32; off <<= 1) acc += __shfl_xor(acc, off, 64);
            float C32 = (float)acc;
            float d32 = __fsub_rn(__fadd_rn(An, B32[k]), __fadd_rn(C32, C32));
            if (d32 < bd || (d32 == bd && k < bk)) { bd = d32; bk = k; }
        }
        if (lane == 0) oidx[n] = (float)bk;
    }
}

// ---------------------------------------------------------------------------
__global__ __launch_bounds__(256) void gather_kernel(const float* __restrict__ cb,
                                                     const float* __restrict__ oidx,
                                                     float* __restrict__ zq) {
    const int tid  = threadIdx.x;
    const int s_nl = tid & 63;
    const int s_dw = tid >> 6;
    const int p0   = blockIdx.x * 64;
    const int b    = p0 >> 10;
    const int hw0  = p0 & 1023;

    int idxn = (int)oidx[p0 + s_nl];
    const float4* crow = reinterpret_cast<const float4*>(cb + (size_t)idxn * D_);
    float* zqb = zq + (size_t)b * (D_ * HW_) + hw0;
    #pragma unroll
    for (int r = 0; r < 16; ++r) {
        int d4 = s_dw * 16 + r;
        float4 c4 = crow[d4];
        int d = d4 * 4;
        zqb[(size_t)(d + 0) * HW_ + s_nl] = c4.x;
        zqb[(size_t)(d + 1) * HW_ + s_nl] = c4.y;
        zqb[(size_t)(d + 2) * HW_ + s_nl] = c4.z;
        zqb[(size_t)(d + 3) * HW_ + s_nl] = c4.w;
    }
}

extern "C" void kernel_launch(void* const* d_in, const int* in_sizes, int n_in,
                              void* d_out, int out_size, void* d_ws, size_t ws_size,
                              hipStream_t stream) {
    const float* z  = (const float*)d_in[0];   // [32,256,32,32] fp32
    const float* cb = (const float*)d_in[1];   // [1024,256] fp32

    float* zq   = (float*)d_out;
    float* oidx = zq + (size_t)N_ * D_;

    char* ws = (char*)d_ws;
    float* B32  = (float*)(ws + 0);
    float* hbF  = (float*)(ws + 4096);
    float* A32  = (float*)(ws + 8192);
    half8* cbAf = (half8*)(ws + 139264);       // FIXED: was 137216 (A32 overlap!)

    half8* zBf = (half8*)zq;                   // 16 MB in zq region

    prep_kernel<<<4356, 256, 0, stream>>>(z, cb, A32, B32, hbF, cbAf, zBf);
    vq_screen11<<<N_ / 64, 256, 0, stream>>>(
        zBf, cbAf, hbF, A32, B32, cb, z, oidx);
    gather_kernel<<<N_ / 64, 256, 0, stream>>>(cb, oidx, zq);
}